// Round 1
// baseline (386.398 us; speedup 1.0000x reference)
//
#include <hip/hip_runtime.h>
#include <hip/hip_bf16.h>
#include <stdint.h>

// MultiHeadAttention on MI355X (gfx950), bf16 MFMA pipeline.
// B=4, S=2048, D=1024, H=16, Dh=64. M = B*S = 8192.

typedef __attribute__((ext_vector_type(4))) float f32x4;
typedef __attribute__((ext_vector_type(8))) short short8;
typedef __attribute__((ext_vector_type(4))) unsigned short ushort4v;

__device__ __forceinline__ unsigned short f2bf(float f) {
    union { float f; unsigned int u; } v; v.f = f;
    unsigned int u = v.u;
    u += 0x7FFFu + ((u >> 16) & 1u);   // RNE
    return (unsigned short)(u >> 16);
}

__device__ __forceinline__ void gll16(const void* g, void* l) {
    __builtin_amdgcn_global_load_lds(
        (const __attribute__((address_space(1))) void*)g,
        (__attribute__((address_space(3))) void*)l, 16, 0, 0);
}

// ---------------- fp32 -> bf16 converts ----------------
__global__ __launch_bounds__(256) void cvtX(const float* __restrict__ src,
                                            unsigned short* __restrict__ dst) {
    int j = (blockIdx.x * 256 + threadIdx.x) * 4;   // grid sized exactly
    float4 v = *(const float4*)(src + j);
    ushort4v o; o.x = f2bf(v.x); o.y = f2bf(v.y); o.z = f2bf(v.z); o.w = f2bf(v.w);
    *(ushort4v*)(dst + j) = o;
}

__global__ __launch_bounds__(256) void cvtW(const float* __restrict__ s0, const float* __restrict__ s1,
                                            const float* __restrict__ s2, const float* __restrict__ s3,
                                            unsigned short* __restrict__ d0, unsigned short* __restrict__ d1,
                                            unsigned short* __restrict__ d2, unsigned short* __restrict__ d3) {
    int t = blockIdx.x >> 10;                       // 1024 blocks per 2^20-elem tensor
    const float* sp = (t == 0) ? s0 : (t == 1) ? s1 : (t == 2) ? s2 : s3;
    unsigned short* dp = (t == 0) ? d0 : (t == 1) ? d1 : (t == 2) ? d2 : d3;
    int j = ((blockIdx.x & 1023) * 256 + threadIdx.x) * 4;
    float4 v = *(const float4*)(sp + j);
    ushort4v o; o.x = f2bf(v.x); o.y = f2bf(v.y); o.z = f2bf(v.z); o.w = f2bf(v.w);
    *(ushort4v*)(dp + j) = o;
}

// ---------------- NT GEMM: C[m,n] = sum_k A[m,k]*W[n,k] + bias[n] ----------------
// MODE 0: bf16 row-major out. MODE 1: bf16 transposed out VT[b][n][s]. MODE 2: f32 row-major out.
// 128x128 tile, BK=32, 256 threads (2x2 waves of 64x64), m97 structure w/ global_load_lds.
template<int MODE>
__global__ __launch_bounds__(256, 2)
void gemm_nt(const unsigned short* __restrict__ A, const unsigned short* __restrict__ Bw,
             const float* __restrict__ bias, void* __restrict__ C) {
    __shared__ unsigned short As[128 * 32];
    __shared__ unsigned short Bs[128 * 32];
    const int tid = threadIdx.x;
    const int wid = tid >> 6, lane = tid & 63;
    const int mtile = blockIdx.x >> 3, ntile = blockIdx.x & 7;   // N/128 = 8
    const int m0 = mtile * 128, n0 = ntile * 128;
    const int wm = (wid >> 1) * 64, wn = (wid & 1) * 64;

    f32x4 acc[4][4];
#pragma unroll
    for (int i = 0; i < 4; i++)
#pragma unroll
        for (int j = 0; j < 4; j++) acc[i][j] = f32x4{0.f, 0.f, 0.f, 0.f};

    // staging: chunk c = issue*256 + tid (16B each); row = c>>2 (64B rows), col8 = (c&3)*8
    const int srow = tid >> 2, scol = (tid & 3) * 8;
    const unsigned short* gA0 = A + (size_t)(m0 + srow) * 1024 + scol;
    const unsigned short* gA1 = A + (size_t)(m0 + 64 + srow) * 1024 + scol;
    const unsigned short* gB0 = Bw + (size_t)(n0 + srow) * 1024 + scol;
    const unsigned short* gB1 = Bw + (size_t)(n0 + 64 + srow) * 1024 + scol;
    char* lA0 = (char*)As + wid * 1024;
    char* lA1 = (char*)As + 4096 + wid * 1024;
    char* lB0 = (char*)Bs + wid * 1024;
    char* lB1 = (char*)Bs + 4096 + wid * 1024;

    const int frow = lane & 15;
    const int fcol = (lane >> 4) * 16;   // byte offset of k-slice

    for (int k0 = 0; k0 < 1024; k0 += 32) {
        gll16(gA0 + k0, lA0);
        gll16(gA1 + k0, lA1);
        gll16(gB0 + k0, lB0);
        gll16(gB1 + k0, lB1);
        __syncthreads();
        short8 af[4], bfr[4];
#pragma unroll
        for (int i = 0; i < 4; i++)
            af[i] = *(const short8*)((const char*)As + (wm + i * 16 + frow) * 64 + fcol);
#pragma unroll
        for (int j = 0; j < 4; j++)
            bfr[j] = *(const short8*)((const char*)Bs + (wn + j * 16 + frow) * 64 + fcol);
#pragma unroll
        for (int i = 0; i < 4; i++)
#pragma unroll
            for (int j = 0; j < 4; j++)
                acc[i][j] = __builtin_amdgcn_mfma_f32_16x16x32_bf16(af[i], bfr[j], acc[i][j], 0, 0, 0);
        __syncthreads();
    }

    // epilogue: C layout col = lane&15, row = (lane>>4)*4 + r  [m89-verified]
#pragma unroll
    for (int i = 0; i < 4; i++) {
#pragma unroll
        for (int j = 0; j < 4; j++) {
            const int n = n0 + wn + j * 16 + (lane & 15);
            const float bv = bias[n];
            if (MODE == 1) {
                const int mbase = m0 + wm + i * 16 + (lane >> 4) * 4;
                ushort4v pk;
#pragma unroll
                for (int r = 0; r < 4; r++) pk[r] = f2bf(acc[i][j][r] + bv);
                const int b = mbase >> 11, s = mbase & 2047;
                *(ushort4v*)((unsigned short*)C + ((size_t)b * 1024 + n) * 2048 + s) = pk;
            } else {
#pragma unroll
                for (int r = 0; r < 4; r++) {
                    const int m = m0 + wm + i * 16 + (lane >> 4) * 4 + r;
                    float v = acc[i][j][r] + bv;
                    if (MODE == 0) ((unsigned short*)C)[(size_t)m * 1024 + n] = f2bf(v);
                    else           ((float*)C)[(size_t)m * 1024 + n] = v;
                }
            }
        }
    }
}

// ---------------- flash attention ----------------
// grid: b(4) x h(16) x qtile(32); block 256 = 4 waves, each wave owns 16 q-rows.
// K_lds[64][72], VT_lds[64][72], P_lds[64][72] (pad 72 kills 128B-row bank conflicts).
__global__ __launch_bounds__(256, 2)
void attn(const unsigned short* __restrict__ Q, const unsigned short* __restrict__ K,
          const unsigned short* __restrict__ VT, unsigned short* __restrict__ O) {
    __shared__ unsigned short Kl[64 * 72];
    __shared__ unsigned short Vl[64 * 72];
    __shared__ unsigned short Pl[64 * 72];
    const int tid = threadIdx.x, wid = tid >> 6, lane = tid & 63;
    const int qt = blockIdx.x & 31, h = (blockIdx.x >> 5) & 15, b = blockIdx.x >> 9;
    const int q0 = qt * 64;
    const int g = lane >> 4, c16 = lane & 15;

    // Q fragments (A-operand): row = l&15, k(d) = (l>>4)*8 + j  (two K=32 halves)
    const int qrow = q0 + wid * 16 + c16;
    const unsigned short* qp = Q + ((size_t)(b * 2048 + qrow)) * 1024 + h * 64 + g * 8;
    short8 aq0 = *(const short8*)qp;
    short8 aq1 = *(const short8*)(qp + 32);

    f32x4 oacc[4];
#pragma unroll
    for (int d = 0; d < 4; d++) oacc[d] = f32x4{0.f, 0.f, 0.f, 0.f};
    float mrun[4], lrun[4];
#pragma unroll
    for (int r = 0; r < 4; r++) { mrun[r] = -1e30f; lrun[r] = 0.f; }

    // staging addresses: thread covers rows sr and sr+32 of both K-tile and VT-tile
    const int sr = tid >> 3, sw8 = (tid & 7) * 8;
    const unsigned short* gK0 = K + ((size_t)(b * 2048 + sr)) * 1024 + h * 64 + sw8;
    const unsigned short* gK1 = K + ((size_t)(b * 2048 + 32 + sr)) * 1024 + h * 64 + sw8;
    const unsigned short* gV0 = VT + ((size_t)(b * 1024 + h * 64 + sr)) * 2048 + sw8;
    const unsigned short* gV1 = VT + ((size_t)(b * 1024 + h * 64 + 32 + sr)) * 2048 + sw8;
    unsigned short* lK0 = Kl + sr * 72 + sw8;
    unsigned short* lK1 = Kl + (32 + sr) * 72 + sw8;
    unsigned short* lV0 = Vl + sr * 72 + sw8;
    unsigned short* lV1 = Vl + (32 + sr) * 72 + sw8;

    for (int kv0 = 0; kv0 < 2048; kv0 += 64) {
        *(short8*)lK0 = *(const short8*)(gK0 + (size_t)kv0 * 1024);
        *(short8*)lK1 = *(const short8*)(gK1 + (size_t)kv0 * 1024);
        *(short8*)lV0 = *(const short8*)(gV0 + kv0);
        *(short8*)lV1 = *(const short8*)(gV1 + kv0);
        __syncthreads();

        // S = Q K^T / 8 : 4 key-subtiles x (2 MFMAs over d)
        f32x4 s[4];
#pragma unroll
        for (int j = 0; j < 4; j++) {
            short8 bk0 = *(const short8*)(Kl + (j * 16 + c16) * 72 + g * 8);
            short8 bk1 = *(const short8*)(Kl + (j * 16 + c16) * 72 + 32 + g * 8);
            f32x4 t = f32x4{0.f, 0.f, 0.f, 0.f};
            t = __builtin_amdgcn_mfma_f32_16x16x32_bf16(aq0, bk0, t, 0, 0, 0);
            t = __builtin_amdgcn_mfma_f32_16x16x32_bf16(aq1, bk1, t, 0, 0, 0);
            s[j] = t * 0.125f;
        }

        // online softmax; row r lives in 16-lane group (shfl_xor masks 1..8 stay in-group)
        float corr[4], rsum[4];
#pragma unroll
        for (int r = 0; r < 4; r++) {
            float mx = fmaxf(fmaxf(s[0][r], s[1][r]), fmaxf(s[2][r], s[3][r]));
#pragma unroll
            for (int off = 1; off < 16; off <<= 1) mx = fmaxf(mx, __shfl_xor(mx, off, 64));
            float nm = fmaxf(mrun[r], mx);
            corr[r] = __expf(mrun[r] - nm);
            mrun[r] = nm;
            rsum[r] = 0.f;
        }
#pragma unroll
        for (int j = 0; j < 4; j++)
#pragma unroll
            for (int r = 0; r < 4; r++) {
                float p = __expf(s[j][r] - mrun[r]);
                s[j][r] = p;
                rsum[r] += p;
            }
#pragma unroll
        for (int r = 0; r < 4; r++) {
            float t = rsum[r];
#pragma unroll
            for (int off = 1; off < 16; off <<= 1) t += __shfl_xor(t, off, 64);
            lrun[r] = lrun[r] * corr[r] + t;
        }
        f32x4 cv; cv.x = corr[0]; cv.y = corr[1]; cv.z = corr[2]; cv.w = corr[3];
#pragma unroll
        for (int d = 0; d < 4; d++) oacc[d] *= cv;

        // P -> LDS (C-layout scatter), then read back as A-fragments
#pragma unroll
        for (int j = 0; j < 4; j++)
#pragma unroll
            for (int r = 0; r < 4; r++)
                Pl[(wid * 16 + g * 4 + r) * 72 + j * 16 + c16] = f2bf(s[j][r]);
        __syncthreads();

        short8 ap0 = *(const short8*)(Pl + (wid * 16 + c16) * 72 + g * 8);
        short8 ap1 = *(const short8*)(Pl + (wid * 16 + c16) * 72 + 32 + g * 8);
#pragma unroll
        for (int d = 0; d < 4; d++) {
            short8 bv0 = *(const short8*)(Vl + (d * 16 + c16) * 72 + g * 8);
            short8 bv1 = *(const short8*)(Vl + (d * 16 + c16) * 72 + 32 + g * 8);
            oacc[d] = __builtin_amdgcn_mfma_f32_16x16x32_bf16(ap0, bv0, oacc[d], 0, 0, 0);
            oacc[d] = __builtin_amdgcn_mfma_f32_16x16x32_bf16(ap1, bv1, oacc[d], 0, 0, 0);
        }
        __syncthreads();
    }

    // epilogue: normalize and store bf16 attention output
#pragma unroll
    for (int d = 0; d < 4; d++)
#pragma unroll
        for (int r = 0; r < 4; r++) {
            const int row = q0 + wid * 16 + g * 4 + r;
            float v = oacc[d][r] / lrun[r];
            O[((size_t)(b * 2048 + row)) * 1024 + h * 64 + d * 16 + c16] = f2bf(v);
        }
}

// ---------------- launch ----------------
extern "C" void kernel_launch(void* const* d_in, const int* in_sizes, int n_in,
                              void* d_out, int out_size, void* d_ws, size_t ws_size,
                              hipStream_t stream) {
    const float* query = (const float*)d_in[0];
    const float* key_  = (const float*)d_in[1];
    const float* value = (const float*)d_in[2];
    const float* Wq = (const float*)d_in[3];
    const float* bq = (const float*)d_in[4];
    const float* Wk = (const float*)d_in[5];
    const float* bk = (const float*)d_in[6];
    const float* Wv = (const float*)d_in[7];
    const float* bv = (const float*)d_in[8];
    const float* Wo = (const float*)d_in[9];
    const float* bo = (const float*)d_in[10];

    char* ws = (char*)d_ws;
    unsigned short* Xbf = (unsigned short*)(ws);                    // 16 MB (also reused as Xattn)
    unsigned short* Wqb = (unsigned short*)(ws + (16ull << 20));    // 2 MB
    unsigned short* Wkb = (unsigned short*)(ws + (18ull << 20));
    unsigned short* Wvb = (unsigned short*)(ws + (20ull << 20));
    unsigned short* Wob = (unsigned short*)(ws + (22ull << 20));
    unsigned short* Qb  = (unsigned short*)(ws + (24ull << 20));    // 16 MB
    unsigned short* Kb  = (unsigned short*)(ws + (40ull << 20));    // 16 MB
    unsigned short* VTb = (unsigned short*)(ws + (56ull << 20));    // 16 MB  (total 72 MB)

    cvtW<<<4096, 256, 0, stream>>>(Wq, Wk, Wv, Wo, Wqb, Wkb, Wvb, Wob);

    cvtX<<<8192, 256, 0, stream>>>(query, Xbf);
    gemm_nt<0><<<512, 256, 0, stream>>>(Xbf, Wqb, bq, Qb);

    cvtX<<<8192, 256, 0, stream>>>(key_, Xbf);
    gemm_nt<0><<<512, 256, 0, stream>>>(Xbf, Wkb, bk, Kb);

    cvtX<<<8192, 256, 0, stream>>>(value, Xbf);
    gemm_nt<1><<<512, 256, 0, stream>>>(Xbf, Wvb, bv, VTb);

    attn<<<2048, 256, 0, stream>>>(Qb, Kb, VTb, Xbf);

    gemm_nt<2><<<512, 256, 0, stream>>>(Xbf, Wob, bo, d_out);
}

// Round 2
// 265.430 us; speedup vs baseline: 1.4557x; 1.4557x over previous
//
#include <hip/hip_runtime.h>
#include <hip/hip_bf16.h>
#include <stdint.h>

// MultiHeadAttention on MI355X (gfx950), bf16 MFMA pipeline.
// B=4, S=2048, D=1024, H=16, Dh=64. M = B*S = 8192.

typedef __attribute__((ext_vector_type(4))) float f32x4;
typedef __attribute__((ext_vector_type(16))) float f32x16;
typedef __attribute__((ext_vector_type(8))) short short8;
typedef __attribute__((ext_vector_type(4))) unsigned short ushort4v;
typedef __attribute__((ext_vector_type(4))) unsigned int uint4v;

__device__ __forceinline__ unsigned short f2bf(float f) {
    union { float f; unsigned int u; } v; v.f = f;
    unsigned int u = v.u;
    u += 0x7FFFu + ((u >> 16) & 1u);   // RNE
    return (unsigned short)(u >> 16);
}

__device__ __forceinline__ void gll16(const void* g, void* l) {
    __builtin_amdgcn_global_load_lds(
        (const __attribute__((address_space(1))) void*)g,
        (__attribute__((address_space(3))) void*)l, 16, 0, 0);
}

__device__ __forceinline__ unsigned int cvtpk_bf16(float lo, float hi) {
    unsigned int r;
    asm("v_cvt_pk_bf16_f32 %0, %1, %2" : "=v"(r) : "v"(lo), "v"(hi));
    return r;
}
// v_permlane32_swap_b32 a, b : a' = {a.lanes0-31, b.lanes0-31}, b' = {a.lanes32-63, b.lanes32-63}
#define PLSWAP(a, b) asm("v_permlane32_swap_b32 %0, %1" : "+v"(a), "+v"(b))

// ---------------- fp32 -> bf16 converts ----------------
__global__ __launch_bounds__(256) void cvtX(const float* __restrict__ src,
                                            unsigned short* __restrict__ dst) {
    int j = (blockIdx.x * 256 + threadIdx.x) * 4;   // grid sized exactly
    float4 v = *(const float4*)(src + j);
    ushort4v o; o.x = f2bf(v.x); o.y = f2bf(v.y); o.z = f2bf(v.z); o.w = f2bf(v.w);
    *(ushort4v*)(dst + j) = o;
}

__global__ __launch_bounds__(256) void cvtW(const float* __restrict__ s0, const float* __restrict__ s1,
                                            const float* __restrict__ s2, const float* __restrict__ s3,
                                            unsigned short* __restrict__ d0, unsigned short* __restrict__ d1,
                                            unsigned short* __restrict__ d2, unsigned short* __restrict__ d3) {
    int t = blockIdx.x >> 10;                       // 1024 blocks per 2^20-elem tensor
    const float* sp = (t == 0) ? s0 : (t == 1) ? s1 : (t == 2) ? s2 : s3;
    unsigned short* dp = (t == 0) ? d0 : (t == 1) ? d1 : (t == 2) ? d2 : d3;
    int j = ((blockIdx.x & 1023) * 256 + threadIdx.x) * 4;
    float4 v = *(const float4*)(sp + j);
    ushort4v o; o.x = f2bf(v.x); o.y = f2bf(v.y); o.z = f2bf(v.z); o.w = f2bf(v.w);
    *(ushort4v*)(dp + j) = o;
}

// ---------------- NT GEMM: C[m,n] = sum_k A[m,k]*W[n,k] + bias[n] ----------------
// MODE 0: bf16 row-major out. MODE 1: bf16 transposed out VT[b][n][s]. MODE 2: f32 row-major out.
// 128x128 tile, BK=32, 256 threads (2x2 waves of 64x64), m97 structure w/ global_load_lds.
template<int MODE>
__global__ __launch_bounds__(256, 2)
void gemm_nt(const unsigned short* __restrict__ A, const unsigned short* __restrict__ Bw,
             const float* __restrict__ bias, void* __restrict__ C) {
    __shared__ unsigned short As[128 * 32];
    __shared__ unsigned short Bs[128 * 32];
    const int tid = threadIdx.x;
    const int wid = tid >> 6, lane = tid & 63;
    const int mtile = blockIdx.x >> 3, ntile = blockIdx.x & 7;   // N/128 = 8
    const int m0 = mtile * 128, n0 = ntile * 128;
    const int wm = (wid >> 1) * 64, wn = (wid & 1) * 64;

    f32x4 acc[4][4];
#pragma unroll
    for (int i = 0; i < 4; i++)
#pragma unroll
        for (int j = 0; j < 4; j++) acc[i][j] = f32x4{0.f, 0.f, 0.f, 0.f};

    const int srow = tid >> 2, scol = (tid & 3) * 8;
    const unsigned short* gA0 = A + (size_t)(m0 + srow) * 1024 + scol;
    const unsigned short* gA1 = A + (size_t)(m0 + 64 + srow) * 1024 + scol;
    const unsigned short* gB0 = Bw + (size_t)(n0 + srow) * 1024 + scol;
    const unsigned short* gB1 = Bw + (size_t)(n0 + 64 + srow) * 1024 + scol;
    char* lA0 = (char*)As + wid * 1024;
    char* lA1 = (char*)As + 4096 + wid * 1024;
    char* lB0 = (char*)Bs + wid * 1024;
    char* lB1 = (char*)Bs + 4096 + wid * 1024;

    const int frow = lane & 15;
    const int fcol = (lane >> 4) * 16;   // byte offset of k-slice

    for (int k0 = 0; k0 < 1024; k0 += 32) {
        gll16(gA0 + k0, lA0);
        gll16(gA1 + k0, lA1);
        gll16(gB0 + k0, lB0);
        gll16(gB1 + k0, lB1);
        __syncthreads();
        short8 af[4], bfr[4];
#pragma unroll
        for (int i = 0; i < 4; i++)
            af[i] = *(const short8*)((const char*)As + (wm + i * 16 + frow) * 64 + fcol);
#pragma unroll
        for (int j = 0; j < 4; j++)
            bfr[j] = *(const short8*)((const char*)Bs + (wn + j * 16 + frow) * 64 + fcol);
#pragma unroll
        for (int i = 0; i < 4; i++)
#pragma unroll
            for (int j = 0; j < 4; j++)
                acc[i][j] = __builtin_amdgcn_mfma_f32_16x16x32_bf16(af[i], bfr[j], acc[i][j], 0, 0, 0);
        __syncthreads();
    }

    // epilogue: C layout col = lane&15, row = (lane>>4)*4 + r  [m89-verified]
#pragma unroll
    for (int i = 0; i < 4; i++) {
#pragma unroll
        for (int j = 0; j < 4; j++) {
            const int n = n0 + wn + j * 16 + (lane & 15);
            const float bv = bias[n];
            if (MODE == 1) {
                const int mbase = m0 + wm + i * 16 + (lane >> 4) * 4;
                ushort4v pk;
#pragma unroll
                for (int r = 0; r < 4; r++) pk[r] = f2bf(acc[i][j][r] + bv);
                const int b = mbase >> 11, s = mbase & 2047;
                *(ushort4v*)((unsigned short*)C + ((size_t)b * 1024 + n) * 2048 + s) = pk;
            } else {
#pragma unroll
                for (int r = 0; r < 4; r++) {
                    const int m = m0 + wm + i * 16 + (lane >> 4) * 4 + r;
                    float v = acc[i][j][r] + bv;
                    if (MODE == 0) ((unsigned short*)C)[(size_t)m * 1024 + n] = f2bf(v);
                    else           ((float*)C)[(size_t)m * 1024 + n] = v;
                }
            }
        }
    }
}

// ---------------- flash attention v2: 32x32 MFMA, swapped QK^T, in-register softmax ----------------
// block 256 = 4 warps; warp owns 32 q-rows -> block = 128 q rows. grid = 4b x 16h x 16qt = 1024.
// K tile [64k x 64d], V^T tile [64d x 64k] in LDS, 128B rows, XOR-swizzled 16B slots
// (slot ^ (row&7)), staged linearly by global_load_lds from inverse-swizzled source (m173/rule 21).
// S^T = mfma(K, Q): lane holds 32 k-values of one q-row -> softmax is in-register + 1 shfl_xor(32).
// P^T -> bf16 B-frags via v_cvt_pk_bf16_f32 + v_permlane32_swap_b32 (T12). O^T = mfma(V^T, P^T).
__global__ __launch_bounds__(256, 3)
void attn2(const unsigned short* __restrict__ Q, const unsigned short* __restrict__ K,
           const unsigned short* __restrict__ VT, unsigned short* __restrict__ O) {
    __shared__ unsigned short Kl[2][64 * 64];
    __shared__ unsigned short Vl[2][64 * 64];
    const int tid = threadIdx.x, wid = tid >> 6, lane = tid & 63;
    const int qt = blockIdx.x & 15, h = (blockIdx.x >> 4) & 15, b = blockIdx.x >> 8;
    const int q0 = qt * 128 + wid * 32;
    const int qcol = lane & 31, g = lane >> 5;
    const int rx7 = qcol & 7;   // (row&7) of the LDS rows this lane reads

    // Q as B-operand fragments: bq[ds] : q = qcol, d = ds*16 + g*8 + j
    short8 bq[4];
    {
        const unsigned short* qp = Q + ((size_t)(b * 2048 + q0 + qcol)) * 1024 + h * 64 + g * 8;
#pragma unroll
        for (int ds = 0; ds < 4; ds++) bq[ds] = *(const short8*)(qp + ds * 16);
    }

    f32x16 oacc[2];
#pragma unroll
    for (int d = 0; d < 2; d++)
#pragma unroll
        for (int i = 0; i < 16; i++) oacc[d][i] = 0.f;
    float mrun = -1e30f, lrun = 0.f;

    // staging: 512 x 16B chunks per tile; chunk c = i*256 + tid -> LDS row c>>3, slot c&7.
    // source supplies global slot sg = (c&7) ^ ((c>>3)&7) so that LDS[row][slot] = G[row][slot^row&7].
    const int srow = wid * 8 + (lane >> 3);            // row for i=0 (i=1 adds 32)
    const int sg = (lane & 7) ^ (lane >> 3);
    const unsigned short* gK0 = K + ((size_t)(b * 2048 + srow)) * 1024 + h * 64 + sg * 8;
    const unsigned short* gK1 = gK0 + (size_t)32 * 1024;
    const unsigned short* gV0 = VT + ((size_t)(b * 1024 + h * 64 + srow)) * 2048 + sg * 8;
    const unsigned short* gV1 = gV0 + (size_t)32 * 2048;

#define ATTN_STAGE(t_, bf_)                                                          \
    do {                                                                             \
        const size_t ko = (size_t)(t_) * 64 * 1024;                                  \
        const size_t vo = (size_t)(t_) * 64;                                         \
        gll16(gK0 + ko, (char*)Kl[bf_] + wid * 1024);                                \
        gll16(gK1 + ko, (char*)Kl[bf_] + 4096 + wid * 1024);                         \
        gll16(gV0 + vo, (char*)Vl[bf_] + wid * 1024);                                \
        gll16(gV1 + vo, (char*)Vl[bf_] + 4096 + wid * 1024);                         \
    } while (0)

    ATTN_STAGE(0, 0);

    for (int t = 0; t < 32; t++) {
        __syncthreads();                       // drains stage(t); all waves done with buf (t-1)
        if (t + 1 < 32) ATTN_STAGE(t + 1, (t + 1) & 1);
        const char* Kt = (const char*)Kl[t & 1];
        const char* Vt = (const char*)Vl[t & 1];

        // ---- S^T[k, q] = sum_d K[k,d] * Q[q,d] ----
        f32x16 st[2];
#pragma unroll
        for (int ks = 0; ks < 2; ks++) {
            const int r = ks * 32 + qcol;
            const char* kr = Kt + r * 128;
            f32x16 s;
#pragma unroll
            for (int i = 0; i < 16; i++) s[i] = 0.f;
#pragma unroll
            for (int ds = 0; ds < 4; ds++) {
                const int slot = ds * 2 + g;
                short8 a = *(const short8*)(kr + ((slot ^ rx7) << 4));
                s = __builtin_amdgcn_mfma_f32_32x32x16_bf16(a, bq[ds], s, 0, 0, 0);
            }
            st[ks] = s;
        }

        // ---- online softmax, fully in-register (lane pair l, l+32 share q-column) ----
        float pm = -1e30f;
#pragma unroll
        for (int ks = 0; ks < 2; ks++)
#pragma unroll
            for (int i = 0; i < 16; i++) pm = fmaxf(pm, st[ks][i]);
        pm = fmaxf(pm, __shfl_xor(pm, 32));
        pm *= 0.125f;                              // 1/sqrt(64)
        const float nm = fmaxf(mrun, pm);
        const float corr = __expf(mrun - nm);
        mrun = nm;
        float ps = 0.f;
#pragma unroll
        for (int ks = 0; ks < 2; ks++)
#pragma unroll
            for (int i = 0; i < 16; i++) {
                float e = __expf(st[ks][i] * 0.125f - nm);
                st[ks][i] = e;
                ps += e;
            }
        ps += __shfl_xor(ps, 32);
        lrun = lrun * corr + ps;
#pragma unroll
        for (int d = 0; d < 2; d++)
#pragma unroll
            for (int i = 0; i < 16; i++) oacc[d][i] *= corr;

        // ---- P^T -> bf16 B-operand fragments (cvt_pk + permlane32_swap, T12) ----
        short8 pb[4];
#pragma unroll
        for (int ks = 0; ks < 2; ks++) {
            unsigned int w[8];
#pragma unroll
            for (int p = 0; p < 8; p++) w[p] = cvtpk_bf16(st[ks][2 * p], st[ks][2 * p + 1]);
            PLSWAP(w[0], w[2]); PLSWAP(w[1], w[3]);   // k-slice 2*ks
            PLSWAP(w[4], w[6]); PLSWAP(w[5], w[7]);   // k-slice 2*ks+1
            uint4v lo = {w[0], w[1], w[2], w[3]};
            uint4v hi = {w[4], w[5], w[6], w[7]};
            pb[2 * ks] = __builtin_bit_cast(short8, lo);
            pb[2 * ks + 1] = __builtin_bit_cast(short8, hi);
        }

        // ---- O^T[d, q] += sum_k V^T[d,k] * P^T[k,q] ----
#pragma unroll
        for (int dsub = 0; dsub < 2; dsub++) {
            const int dr = dsub * 32 + qcol;
            const char* vr = Vt + dr * 128;
            f32x16 o = oacc[dsub];
#pragma unroll
            for (int kb = 0; kb < 4; kb++) {
                const int slot = kb * 2 + g;
                short8 a = *(const short8*)(vr + ((slot ^ rx7) << 4));
                o = __builtin_amdgcn_mfma_f32_32x32x16_bf16(a, pb[kb], o, 0, 0, 0);
            }
            oacc[dsub] = o;
        }
    }
#undef ATTN_STAGE

    // ---- epilogue: O[q][d] = O^T[d][q] / lrun ----
    const float inv = 1.f / lrun;
    unsigned short* orow = O + ((size_t)(b * 2048 + q0 + qcol)) * 1024 + h * 64;
#pragma unroll
    for (int dsub = 0; dsub < 2; dsub++)
#pragma unroll
        for (int q4 = 0; q4 < 4; q4++) {
            ushort4v pk;
#pragma unroll
            for (int rr = 0; rr < 4; rr++) pk[rr] = f2bf(oacc[dsub][q4 * 4 + rr] * inv);
            const int d0 = dsub * 32 + q4 * 8 + g * 4;   // d = dsub*32 + rr + 8*q4 + 4g
            *(ushort4v*)(orow + d0) = pk;
        }
}

// ---------------- launch ----------------
extern "C" void kernel_launch(void* const* d_in, const int* in_sizes, int n_in,
                              void* d_out, int out_size, void* d_ws, size_t ws_size,
                              hipStream_t stream) {
    const float* query = (const float*)d_in[0];
    const float* key_  = (const float*)d_in[1];
    const float* value = (const float*)d_in[2];
    const float* Wq = (const float*)d_in[3];
    const float* bq = (const float*)d_in[4];
    const float* Wk = (const float*)d_in[5];
    const float* bk = (const float*)d_in[6];
    const float* Wv = (const float*)d_in[7];
    const float* bv = (const float*)d_in[8];
    const float* Wo = (const float*)d_in[9];
    const float* bo = (const float*)d_in[10];

    char* ws = (char*)d_ws;
    unsigned short* Xbf = (unsigned short*)(ws);                    // 16 MB (reused as attn out)
    unsigned short* Wqb = (unsigned short*)(ws + (16ull << 20));    // 2 MB
    unsigned short* Wkb = (unsigned short*)(ws + (18ull << 20));
    unsigned short* Wvb = (unsigned short*)(ws + (20ull << 20));
    unsigned short* Wob = (unsigned short*)(ws + (22ull << 20));
    unsigned short* Qb  = (unsigned short*)(ws + (24ull << 20));    // 16 MB
    unsigned short* Kb  = (unsigned short*)(ws + (40ull << 20));    // 16 MB
    unsigned short* VTb = (unsigned short*)(ws + (56ull << 20));    // 16 MB  (total 72 MB)

    cvtW<<<4096, 256, 0, stream>>>(Wq, Wk, Wv, Wo, Wqb, Wkb, Wvb, Wob);

    cvtX<<<8192, 256, 0, stream>>>(query, Xbf);
    gemm_nt<0><<<512, 256, 0, stream>>>(Xbf, Wqb, bq, Qb);

    cvtX<<<8192, 256, 0, stream>>>(key_, Xbf);
    gemm_nt<0><<<512, 256, 0, stream>>>(Xbf, Wkb, bk, Kb);

    cvtX<<<8192, 256, 0, stream>>>(value, Xbf);
    gemm_nt<1><<<512, 256, 0, stream>>>(Xbf, Wvb, bv, VTb);

    attn2<<<1024, 256, 0, stream>>>(Qb, Kb, VTb, Xbf);

    gemm_nt<2><<<512, 256, 0, stream>>>(Xbf, Wob, bo, d_out);
}

// Round 5
// 248.571 us; speedup vs baseline: 1.5545x; 1.0678x over previous
//
#include <hip/hip_runtime.h>
#include <hip/hip_bf16.h>
#include <stdint.h>

// MultiHeadAttention on MI355X (gfx950), bf16 MFMA pipeline.
// B=4, S=2048, D=1024, H=16, Dh=64. M = B*S = 8192.

typedef __attribute__((ext_vector_type(4))) float f32x4;
typedef __attribute__((ext_vector_type(16))) float f32x16;
typedef __attribute__((ext_vector_type(8))) short short8;
typedef __attribute__((ext_vector_type(4))) unsigned short ushort4v;
typedef __attribute__((ext_vector_type(4))) unsigned int uint4v;

#define SCALE_Q 0.1803368801111f   // 0.125 * log2(e): softmax runs in exp2 domain
#define EXP2(x) __builtin_amdgcn_exp2f(x)

__device__ __forceinline__ unsigned short f2bf(float f) {
    union { float f; unsigned int u; } v; v.f = f;
    unsigned int u = v.u;
    u += 0x7FFFu + ((u >> 16) & 1u);   // RNE
    return (unsigned short)(u >> 16);
}

__device__ __forceinline__ void gll16(const void* g, void* l) {
    __builtin_amdgcn_global_load_lds(
        (const __attribute__((address_space(1))) void*)g,
        (__attribute__((address_space(3))) void*)l, 16, 0, 0);
}

__device__ __forceinline__ unsigned int cvtpk_bf16(float lo, float hi) {
    unsigned int r;
    asm("v_cvt_pk_bf16_f32 %0, %1, %2" : "=v"(r) : "v"(lo), "v"(hi));
    return r;
}
// v_permlane32_swap_b32 a, b : a' = {a.lanes0-31, b.lanes0-31}, b' = {a.lanes32-63, b.lanes32-63}
// ONLY safe with provably-distinct operand values (same-value operands may be register-coalesced
// by the allocator, degenerating the swap — the r3/r4 accuracy bug).
#define PLSWAP(a, b) asm("v_permlane32_swap_b32 %0, %1" : "+v"(a), "+v"(b))

// ---------------- fp32 -> bf16 converts ----------------
__global__ __launch_bounds__(256) void cvtX(const float* __restrict__ src,
                                            unsigned short* __restrict__ dst) {
    int j = (blockIdx.x * 256 + threadIdx.x) * 4;   // grid sized exactly
    float4 v = *(const float4*)(src + j);
    ushort4v o; o.x = f2bf(v.x); o.y = f2bf(v.y); o.z = f2bf(v.z); o.w = f2bf(v.w);
    *(ushort4v*)(dst + j) = o;
}

__global__ __launch_bounds__(256) void cvtW(const float* __restrict__ s0, const float* __restrict__ s1,
                                            const float* __restrict__ s2, const float* __restrict__ s3,
                                            unsigned short* __restrict__ d0, unsigned short* __restrict__ d1,
                                            unsigned short* __restrict__ d2, unsigned short* __restrict__ d3) {
    int t = blockIdx.x >> 10;                       // 1024 blocks per 2^20-elem tensor
    const float* sp = (t == 0) ? s0 : (t == 1) ? s1 : (t == 2) ? s2 : s3;
    unsigned short* dp = (t == 0) ? d0 : (t == 1) ? d1 : (t == 2) ? d2 : d3;
    int j = ((blockIdx.x & 1023) * 256 + threadIdx.x) * 4;
    float4 v = *(const float4*)(sp + j);
    ushort4v o; o.x = f2bf(v.x); o.y = f2bf(v.y); o.z = f2bf(v.z); o.w = f2bf(v.w);
    *(ushort4v*)(dp + j) = o;
}

// ---------------- NT GEMM: C[m,n] = sum_k A[m,k]*W[n,k] + bias[n] ----------------
// MODE 0: bf16 row-major. MODE 1: bf16 transposed VT[b][n][s]. MODE 2: f32 row-major.
// MODE 3: bf16 row-major scaled by SCALE_Q (Q projection; folds softmax scale+log2e).
template<int MODE>
__global__ __launch_bounds__(256, 2)
void gemm_nt(const unsigned short* __restrict__ A, const unsigned short* __restrict__ Bw,
             const float* __restrict__ bias, void* __restrict__ C) {
    __shared__ unsigned short As[128 * 32];
    __shared__ unsigned short Bs[128 * 32];
    const int tid = threadIdx.x;
    const int wid = tid >> 6, lane = tid & 63;
    const int mtile = blockIdx.x >> 3, ntile = blockIdx.x & 7;   // N/128 = 8
    const int m0 = mtile * 128, n0 = ntile * 128;
    const int wm = (wid >> 1) * 64, wn = (wid & 1) * 64;

    f32x4 acc[4][4];
#pragma unroll
    for (int i = 0; i < 4; i++)
#pragma unroll
        for (int j = 0; j < 4; j++) acc[i][j] = f32x4{0.f, 0.f, 0.f, 0.f};

    const int srow = tid >> 2, scol = (tid & 3) * 8;
    const unsigned short* gA0 = A + (size_t)(m0 + srow) * 1024 + scol;
    const unsigned short* gA1 = A + (size_t)(m0 + 64 + srow) * 1024 + scol;
    const unsigned short* gB0 = Bw + (size_t)(n0 + srow) * 1024 + scol;
    const unsigned short* gB1 = Bw + (size_t)(n0 + 64 + srow) * 1024 + scol;
    char* lA0 = (char*)As + wid * 1024;
    char* lA1 = (char*)As + 4096 + wid * 1024;
    char* lB0 = (char*)Bs + wid * 1024;
    char* lB1 = (char*)Bs + 4096 + wid * 1024;

    const int frow = lane & 15;
    const int fcol = (lane >> 4) * 16;   // byte offset of k-slice

    for (int k0 = 0; k0 < 1024; k0 += 32) {
        gll16(gA0 + k0, lA0);
        gll16(gA1 + k0, lA1);
        gll16(gB0 + k0, lB0);
        gll16(gB1 + k0, lB1);
        __syncthreads();
        short8 af[4], bfr[4];
#pragma unroll
        for (int i = 0; i < 4; i++)
            af[i] = *(const short8*)((const char*)As + (wm + i * 16 + frow) * 64 + fcol);
#pragma unroll
        for (int j = 0; j < 4; j++)
            bfr[j] = *(const short8*)((const char*)Bs + (wn + j * 16 + frow) * 64 + fcol);
#pragma unroll
        for (int i = 0; i < 4; i++)
#pragma unroll
            for (int j = 0; j < 4; j++)
                acc[i][j] = __builtin_amdgcn_mfma_f32_16x16x32_bf16(af[i], bfr[j], acc[i][j], 0, 0, 0);
        __syncthreads();
    }

    // epilogue: C layout col = lane&15, row = (lane>>4)*4 + r  [m89-verified]
#pragma unroll
    for (int i = 0; i < 4; i++) {
#pragma unroll
        for (int j = 0; j < 4; j++) {
            const int n = n0 + wn + j * 16 + (lane & 15);
            const float bv = bias[n];
            if (MODE == 1) {
                const int mbase = m0 + wm + i * 16 + (lane >> 4) * 4;
                ushort4v pk;
#pragma unroll
                for (int r = 0; r < 4; r++) pk[r] = f2bf(acc[i][j][r] + bv);
                const int b = mbase >> 11, s = mbase & 2047;
                *(ushort4v*)((unsigned short*)C + ((size_t)b * 1024 + n) * 2048 + s) = pk;
            } else {
#pragma unroll
                for (int r = 0; r < 4; r++) {
                    const int m = m0 + wm + i * 16 + (lane >> 4) * 4 + r;
                    float v = acc[i][j][r] + bv;
                    if (MODE == 0) ((unsigned short*)C)[(size_t)m * 1024 + n] = f2bf(v);
                    else if (MODE == 3) ((unsigned short*)C)[(size_t)m * 1024 + n] = f2bf(v * SCALE_Q);
                    else ((float*)C)[(size_t)m * 1024 + n] = v;
                }
            }
        }
    }
}

// ---------------- flash attention v5: 32x32 MFMA, exp2 domain, shfl cross-half ----------------
// block 256 = 4 warps; warp owns 32 q-rows -> block = 128 q rows. grid = 1024 (XCD-swizzled).
// K tile [64k x 64d], V^T tile [64d x 64k] in LDS, 128B rows, XOR-swizzled 16B slots
// (slot ^ (row&7)), staged linearly by global_load_lds from inverse-swizzled source.
// S^T = mfma(K, Q): lane holds 32 k-vals of one q-row. Q pre-scaled by 0.125*log2e at
// projection; p = exp2(st - m). Cross-half max/sum exchange via __shfl_xor (r2-proven;
// PLSWAP with same-value operands is unsafe — register coalescing degenerates it).
__global__ __launch_bounds__(256, 4)
void attn2(const unsigned short* __restrict__ Q, const unsigned short* __restrict__ K,
           const unsigned short* __restrict__ VT, unsigned short* __restrict__ O) {
    __shared__ unsigned short Kl[2][64 * 64];
    __shared__ unsigned short Vl[2][64 * 64];
    const int tid = threadIdx.x, wid = tid >> 6, lane = tid & 63;
    // XCD-aware decode: xcd = x&7 fixed by dispatch; qt varies fastest within an xcd,
    // so each XCD's resident blocks share few (b,h) K/V sets (fits per-XCD L2).
    const int x = blockIdx.x;
    const int i_ = x >> 3;
    const int qt = i_ & 15;
    const int bh = (x & 7) + 8 * (i_ >> 4);
    const int b = bh >> 4, h = bh & 15;
    const int q0 = qt * 128 + wid * 32;
    const int qcol = lane & 31, g = lane >> 5;
    const int rx7 = qcol & 7;   // (row&7) of the LDS rows this lane reads

    // Q as B-operand fragments: bq[ds] : q = qcol, d = ds*16 + g*8 + j  (pre-scaled)
    short8 bq[4];
    {
        const unsigned short* qp = Q + ((size_t)(b * 2048 + q0 + qcol)) * 1024 + h * 64 + g * 8;
#pragma unroll
        for (int ds = 0; ds < 4; ds++) bq[ds] = *(const short8*)(qp + ds * 16);
    }

    f32x16 oacc0, oacc1;
#pragma unroll
    for (int i = 0; i < 16; i++) { oacc0[i] = 0.f; oacc1[i] = 0.f; }
    float mrun = -1e30f, lrun = 0.f;

    // staging: 512 x 16B chunks per tile; chunk c = i*256 + tid -> LDS row c>>3, slot c&7.
    // source supplies global slot sg = (c&7) ^ ((c>>3)&7) so LDS[row][slot] = G[row][slot^row&7].
    const int srow = wid * 8 + (lane >> 3);
    const int sg = (lane & 7) ^ (lane >> 3);
    const unsigned short* gK0 = K + ((size_t)(b * 2048 + srow)) * 1024 + h * 64 + sg * 8;
    const unsigned short* gK1 = gK0 + (size_t)32 * 1024;
    const unsigned short* gV0 = VT + ((size_t)(b * 1024 + h * 64 + srow)) * 2048 + sg * 8;
    const unsigned short* gV1 = gV0 + (size_t)32 * 2048;

#define ATTN_STAGE(t_, bf_)                                                          \
    do {                                                                             \
        const size_t ko = (size_t)(t_) * 64 * 1024;                                  \
        const size_t vo = (size_t)(t_) * 64;                                         \
        gll16(gK0 + ko, (char*)Kl[bf_] + wid * 1024);                                \
        gll16(gK1 + ko, (char*)Kl[bf_] + 4096 + wid * 1024);                         \
        gll16(gV0 + vo, (char*)Vl[bf_] + wid * 1024);                                \
        gll16(gV1 + vo, (char*)Vl[bf_] + 4096 + wid * 1024);                         \
    } while (0)

    ATTN_STAGE(0, 0);

    for (int t = 0; t < 32; t++) {
        __syncthreads();                       // drains stage(t); all waves done with buf (t-1)
        if (t + 1 < 32) ATTN_STAGE(t + 1, (t + 1) & 1);
        const char* Kt = (const char*)Kl[t & 1];
        const char* Vt = (const char*)Vl[t & 1];

        // ---- S^T[k, q] = sum_d K[k,d] * Q[q,d]  (already in exp2-scaled units) ----
        f32x16 st0, st1;
#pragma unroll
        for (int i = 0; i < 16; i++) { st0[i] = 0.f; st1[i] = 0.f; }
        __builtin_amdgcn_s_setprio(1);
        {
            const char* kr0 = Kt + (qcol)*128;
            const char* kr1 = Kt + (32 + qcol) * 128;
#pragma unroll
            for (int ds = 0; ds < 4; ds++) {
                const int slot = ds * 2 + g;
                short8 a0 = *(const short8*)(kr0 + ((slot ^ rx7) << 4));
                short8 a1 = *(const short8*)(kr1 + ((slot ^ rx7) << 4));
                st0 = __builtin_amdgcn_mfma_f32_32x32x16_bf16(a0, bq[ds], st0, 0, 0, 0);
                st1 = __builtin_amdgcn_mfma_f32_32x32x16_bf16(a1, bq[ds], st1, 0, 0, 0);
            }
        }
        __builtin_amdgcn_s_setprio(0);

        // ---- tile max (tree + shfl cross-half exchange) ----
        float tm[8];
#pragma unroll
        for (int i = 0; i < 8; i++)
            tm[i] = fmaxf(fmaxf(st0[i], st0[i + 8]), fmaxf(st1[i], st1[i + 8]));
#pragma unroll
        for (int i = 0; i < 4; i++) tm[i] = fmaxf(tm[i], tm[i + 4]);
        float pm = fmaxf(fmaxf(tm[0], tm[1]), fmaxf(tm[2], tm[3]));
        pm = fmaxf(pm, __shfl_xor(pm, 32));

        // ---- online softmax, true running max (r2-verified numerics) ----
        const float nm = fmaxf(mrun, pm);
        const float corr = EXP2(mrun - nm);
        mrun = nm;

        // ---- p = exp2(st - m); sum (vector tree) ----
        f32x16 p0, p1;
#pragma unroll
        for (int i = 0; i < 16; i++) {
            p0[i] = EXP2(st0[i] - nm);
            p1[i] = EXP2(st1[i] - nm);
        }
        float ts[8];
#pragma unroll
        for (int i = 0; i < 8; i++) ts[i] = (p0[i] + p0[i + 8]) + (p1[i] + p1[i + 8]);
#pragma unroll
        for (int i = 0; i < 4; i++) ts[i] += ts[i + 4];
        float ps = (ts[0] + ts[1]) + (ts[2] + ts[3]);
        ps += __shfl_xor(ps, 32);
        lrun = lrun * corr + ps;
#pragma unroll
        for (int i = 0; i < 16; i++) { oacc0[i] *= corr; oacc1[i] *= corr; }

        // ---- P^T -> bf16 B-operand fragments (cvt_pk + permlane32_swap, T12) ----
        short8 pb[4];
        {
            unsigned int w[8];
#pragma unroll
            for (int p = 0; p < 8; p++) w[p] = cvtpk_bf16(p0[2 * p], p0[2 * p + 1]);
            PLSWAP(w[0], w[2]); PLSWAP(w[1], w[3]);
            PLSWAP(w[4], w[6]); PLSWAP(w[5], w[7]);
            uint4v lo = {w[0], w[1], w[2], w[3]};
            uint4v hi = {w[4], w[5], w[6], w[7]};
            pb[0] = __builtin_bit_cast(short8, lo);
            pb[1] = __builtin_bit_cast(short8, hi);
        }
        {
            unsigned int w[8];
#pragma unroll
            for (int p = 0; p < 8; p++) w[p] = cvtpk_bf16(p1[2 * p], p1[2 * p + 1]);
            PLSWAP(w[0], w[2]); PLSWAP(w[1], w[3]);
            PLSWAP(w[4], w[6]); PLSWAP(w[5], w[7]);
            uint4v lo = {w[0], w[1], w[2], w[3]};
            uint4v hi = {w[4], w[5], w[6], w[7]};
            pb[2] = __builtin_bit_cast(short8, lo);
            pb[3] = __builtin_bit_cast(short8, hi);
        }

        // ---- O^T[d, q] += sum_k V^T[d,k] * P^T[k,q] ----
        __builtin_amdgcn_s_setprio(1);
        {
            const char* vr0 = Vt + (qcol)*128;
            const char* vr1 = Vt + (32 + qcol) * 128;
#pragma unroll
            for (int kb = 0; kb < 4; kb++) {
                const int slot = kb * 2 + g;
                short8 a0 = *(const short8*)(vr0 + ((slot ^ rx7) << 4));
                short8 a1 = *(const short8*)(vr1 + ((slot ^ rx7) << 4));
                oacc0 = __builtin_amdgcn_mfma_f32_32x32x16_bf16(a0, pb[kb], oacc0, 0, 0, 0);
                oacc1 = __builtin_amdgcn_mfma_f32_32x32x16_bf16(a1, pb[kb], oacc1, 0, 0, 0);
            }
        }
        __builtin_amdgcn_s_setprio(0);
    }
#undef ATTN_STAGE

    // ---- epilogue: O[q][d] = O^T[d][q] / lrun ----
    const float inv = 1.f / lrun;
    unsigned short* orow = O + ((size_t)(b * 2048 + q0 + qcol)) * 1024 + h * 64;
#pragma unroll
    for (int dsub = 0; dsub < 2; dsub++)
#pragma unroll
        for (int q4 = 0; q4 < 4; q4++) {
            ushort4v pk;
#pragma unroll
            for (int rr = 0; rr < 4; rr++) {
                float v = (dsub == 0 ? oacc0[q4 * 4 + rr] : oacc1[q4 * 4 + rr]) * inv;
                pk[rr] = f2bf(v);
            }
            const int d0 = dsub * 32 + q4 * 8 + g * 4;
            *(ushort4v*)(orow + d0) = pk;
        }
}

// ---------------- launch ----------------
extern "C" void kernel_launch(void* const* d_in, const int* in_sizes, int n_in,
                              void* d_out, int out_size, void* d_ws, size_t ws_size,
                              hipStream_t stream) {
    const float* query = (const float*)d_in[0];
    const float* key_  = (const float*)d_in[1];
    const float* value = (const float*)d_in[2];
    const float* Wq = (const float*)d_in[3];
    const float* bq = (const float*)d_in[4];
    const float* Wk = (const float*)d_in[5];
    const float* bk = (const float*)d_in[6];
    const float* Wv = (const float*)d_in[7];
    const float* bv = (const float*)d_in[8];
    const float* Wo = (const float*)d_in[9];
    const float* bo = (const float*)d_in[10];

    char* ws = (char*)d_ws;
    unsigned short* Xbf = (unsigned short*)(ws);                    // 16 MB (reused as attn out)
    unsigned short* Wqb = (unsigned short*)(ws + (16ull << 20));    // 2 MB
    unsigned short* Wkb = (unsigned short*)(ws + (18ull << 20));
    unsigned short* Wvb = (unsigned short*)(ws + (20ull << 20));
    unsigned short* Wob = (unsigned short*)(ws + (22ull << 20));
    unsigned short* Qb  = (unsigned short*)(ws + (24ull << 20));    // 16 MB
    unsigned short* Kb  = (unsigned short*)(ws + (40ull << 20));    // 16 MB
    unsigned short* VTb = (unsigned short*)(ws + (56ull << 20));    // 16 MB  (total 72 MB)

    cvtW<<<4096, 256, 0, stream>>>(Wq, Wk, Wv, Wo, Wqb, Wkb, Wvb, Wob);

    cvtX<<<8192, 256, 0, stream>>>(query, Xbf);
    gemm_nt<3><<<512, 256, 0, stream>>>(Xbf, Wqb, bq, Qb);   // Q pre-scaled for exp2 softmax

    cvtX<<<8192, 256, 0, stream>>>(key_, Xbf);
    gemm_nt<0><<<512, 256, 0, stream>>>(Xbf, Wkb, bk, Kb);

    cvtX<<<8192, 256, 0, stream>>>(value, Xbf);
    gemm_nt<1><<<512, 256, 0, stream>>>(Xbf, Wvb, bv, VTb);

    attn2<<<1024, 256, 0, stream>>>(Qb, Kb, VTb, Xbf);

    gemm_nt<2><<<512, 256, 0, stream>>>(Xbf, Wob, bo, d_out);
}

// Round 6
// 237.196 us; speedup vs baseline: 1.6290x; 1.0480x over previous
//
#include <hip/hip_runtime.h>
#include <hip/hip_bf16.h>
#include <stdint.h>

// MultiHeadAttention on MI355X (gfx950), bf16 MFMA pipeline.
// B=4, S=2048, D=1024, H=16, Dh=64. M = B*S = 8192.

typedef __attribute__((ext_vector_type(4))) float f32x4;
typedef __attribute__((ext_vector_type(16))) float f32x16;
typedef __attribute__((ext_vector_type(8))) short short8;
typedef __attribute__((ext_vector_type(4))) unsigned short ushort4v;
typedef __attribute__((ext_vector_type(4))) unsigned int uint4v;

#define SCALE_Q 0.1803368801111f   // 0.125 * log2(e): softmax runs in exp2 domain
#define EXP2(x) __builtin_amdgcn_exp2f(x)

__device__ __forceinline__ unsigned short f2bf(float f) {
    union { float f; unsigned int u; } v; v.f = f;
    unsigned int u = v.u;
    u += 0x7FFFu + ((u >> 16) & 1u);   // RNE
    return (unsigned short)(u >> 16);
}

__device__ __forceinline__ void gll16(const void* g, void* l) {
    __builtin_amdgcn_global_load_lds(
        (const __attribute__((address_space(1))) void*)g,
        (__attribute__((address_space(3))) void*)l, 16, 0, 0);
}

// v_cvt_pk_bf16_f32: RNE (LLVM lowers fptrunc f32->bf16 to this on gfx950)
__device__ __forceinline__ unsigned int cvtpk_bf16(float lo, float hi) {
    unsigned int r;
    asm("v_cvt_pk_bf16_f32 %0, %1, %2" : "=v"(r) : "v"(lo), "v"(hi));
    return r;
}
// v_permlane32_swap_b32 a, b : a' = {a.lanes0-31, b.lanes0-31}, b' = {a.lanes32-63, b.lanes32-63}
// ONLY safe with provably-distinct operand values (same-value operands may be register-coalesced
// by the allocator, degenerating the swap — the r3/r4 accuracy bug).
#define PLSWAP(a, b) asm("v_permlane32_swap_b32 %0, %1" : "+v"(a), "+v"(b))

// ---------------- fp32 -> bf16 weight convert ----------------
__global__ __launch_bounds__(256) void cvtW(const float* __restrict__ s0, const float* __restrict__ s1,
                                            const float* __restrict__ s2, const float* __restrict__ s3,
                                            unsigned short* __restrict__ d0, unsigned short* __restrict__ d1,
                                            unsigned short* __restrict__ d2, unsigned short* __restrict__ d3) {
    int t = blockIdx.x >> 10;                       // 1024 blocks per 2^20-elem tensor
    const float* sp = (t == 0) ? s0 : (t == 1) ? s1 : (t == 2) ? s2 : s3;
    unsigned short* dp = (t == 0) ? d0 : (t == 1) ? d1 : (t == 2) ? d2 : d3;
    int j = ((blockIdx.x & 1023) * 256 + threadIdx.x) * 4;
    float4 v = *(const float4*)(sp + j);
    ushort4v o; o.x = f2bf(v.x); o.y = f2bf(v.y); o.z = f2bf(v.z); o.w = f2bf(v.w);
    *(ushort4v*)(dp + j) = o;
}

// ---------------- NT GEMM: C[m,n] = sum_k A[m,k]*W[n,k] + bias[n] ----------------
// MODE 0: bf16 row-major. MODE 1: bf16 transposed VT[b][n][s]. MODE 2: f32 row-major.
// MODE 3: bf16 row-major scaled by SCALE_Q (Q projection; folds softmax scale+log2e).
// F32A 1: A is fp32; converted to bf16 in-kernel (reg-staged, prefetched one K-step ahead).
// XCD-contiguous decode: xcd = blockIdx&7 owns mtiles [8*xcd, 8*xcd+8) x all ntiles,
// so each XCD's A-panels (2MB) + B (2MB) stay resident in its private L2.
template<int MODE, int F32A>
__global__ __launch_bounds__(256, 2)
void gemm_nt(const void* __restrict__ Asrc, const unsigned short* __restrict__ Bw,
             const float* __restrict__ bias, void* __restrict__ C) {
    __shared__ unsigned short As[128 * 32];
    __shared__ unsigned short Bs[128 * 32];
    const int tid = threadIdx.x;
    const int wid = tid >> 6, lane = tid & 63;
    const int xcd = blockIdx.x & 7, j_ = blockIdx.x >> 3;    // 512 blocks
    const int mtile = xcd * 8 + (j_ >> 3), ntile = j_ & 7;
    const int m0 = mtile * 128, n0 = ntile * 128;
    const int wm = (wid >> 1) * 64, wn = (wid & 1) * 64;

    f32x4 acc[4][4];
#pragma unroll
    for (int i = 0; i < 4; i++)
#pragma unroll
        for (int j = 0; j < 4; j++) acc[i][j] = f32x4{0.f, 0.f, 0.f, 0.f};

    const int srow = tid >> 2, scol = (tid & 3) * 8;
    const unsigned short* gB0 = Bw + (size_t)(n0 + srow) * 1024 + scol;
    const unsigned short* gB1 = Bw + (size_t)(n0 + 64 + srow) * 1024 + scol;
    char* lB0 = (char*)Bs + wid * 1024;
    char* lB1 = (char*)Bs + 4096 + wid * 1024;

    // A staging pointers
    const unsigned short* gA0 = nullptr; const unsigned short* gA1 = nullptr;
    const float* gAf0 = nullptr; const float* gAf1 = nullptr;
    char* lA0 = (char*)As + wid * 1024;
    char* lA1 = (char*)As + 4096 + wid * 1024;
    if (F32A) {
        gAf0 = (const float*)Asrc + (size_t)(m0 + srow) * 1024 + scol;
        gAf1 = (const float*)Asrc + (size_t)(m0 + 64 + srow) * 1024 + scol;
    } else {
        gA0 = (const unsigned short*)Asrc + (size_t)(m0 + srow) * 1024 + scol;
        gA1 = (const unsigned short*)Asrc + (size_t)(m0 + 64 + srow) * 1024 + scol;
    }

    const int frow = lane & 15;
    const int fcol = (lane >> 4) * 16;   // byte offset of k-slice

    float4 p00, p01, p10, p11;           // fp32 A prefetch registers (F32A)
    if (F32A) {
        p00 = *(const float4*)(gAf0);
        p01 = *(const float4*)(gAf0 + 4);
        p10 = *(const float4*)(gAf1);
        p11 = *(const float4*)(gAf1 + 4);
    }

    for (int k0 = 0; k0 < 1024; k0 += 32) {
        gll16(gB0 + k0, lB0);
        gll16(gB1 + k0, lB1);
        if (F32A) {
            // convert prefetched fp32 -> bf16, write linearly (chunk tid -> byte tid*16)
            uint4v wa = {cvtpk_bf16(p00.x, p00.y), cvtpk_bf16(p00.z, p00.w),
                         cvtpk_bf16(p01.x, p01.y), cvtpk_bf16(p01.z, p01.w)};
            uint4v wb = {cvtpk_bf16(p10.x, p10.y), cvtpk_bf16(p10.z, p10.w),
                         cvtpk_bf16(p11.x, p11.y), cvtpk_bf16(p11.z, p11.w)};
            *(uint4v*)((char*)As + tid * 16) = wa;
            *(uint4v*)((char*)As + 4096 + tid * 16) = wb;
        } else {
            gll16(gA0 + k0, lA0);
            gll16(gA1 + k0, lA1);
        }
        __syncthreads();
        if (F32A && k0 + 32 < 1024) {    // prefetch next K-step under the MFMA phase
            p00 = *(const float4*)(gAf0 + k0 + 32);
            p01 = *(const float4*)(gAf0 + k0 + 36);
            p10 = *(const float4*)(gAf1 + k0 + 32);
            p11 = *(const float4*)(gAf1 + k0 + 36);
        }
        short8 af[4], bfr[4];
#pragma unroll
        for (int i = 0; i < 4; i++)
            af[i] = *(const short8*)((const char*)As + (wm + i * 16 + frow) * 64 + fcol);
#pragma unroll
        for (int j = 0; j < 4; j++)
            bfr[j] = *(const short8*)((const char*)Bs + (wn + j * 16 + frow) * 64 + fcol);
#pragma unroll
        for (int i = 0; i < 4; i++)
#pragma unroll
            for (int j = 0; j < 4; j++)
                acc[i][j] = __builtin_amdgcn_mfma_f32_16x16x32_bf16(af[i], bfr[j], acc[i][j], 0, 0, 0);
        __syncthreads();
    }

    // epilogue: C layout col = lane&15, row = (lane>>4)*4 + r  [m89-verified]
#pragma unroll
    for (int i = 0; i < 4; i++) {
#pragma unroll
        for (int j = 0; j < 4; j++) {
            const int n = n0 + wn + j * 16 + (lane & 15);
            const float bv = bias[n];
            if (MODE == 1) {
                const int mbase = m0 + wm + i * 16 + (lane >> 4) * 4;
                ushort4v pk;
#pragma unroll
                for (int r = 0; r < 4; r++) pk[r] = f2bf(acc[i][j][r] + bv);
                const int b = mbase >> 11, s = mbase & 2047;
                *(ushort4v*)((unsigned short*)C + ((size_t)b * 1024 + n) * 2048 + s) = pk;
            } else {
#pragma unroll
                for (int r = 0; r < 4; r++) {
                    const int m = m0 + wm + i * 16 + (lane >> 4) * 4 + r;
                    float v = acc[i][j][r] + bv;
                    if (MODE == 0) ((unsigned short*)C)[(size_t)m * 1024 + n] = f2bf(v);
                    else if (MODE == 3) ((unsigned short*)C)[(size_t)m * 1024 + n] = f2bf(v * SCALE_Q);
                    else ((float*)C)[(size_t)m * 1024 + n] = v;
                }
            }
        }
    }
}

// ---------------- flash attention v5: 32x32 MFMA, exp2 domain, shfl cross-half ----------------
// block 256 = 4 warps; warp owns 32 q-rows -> block = 128 q rows. grid = 1024 (XCD-swizzled).
// K tile [64k x 64d], V^T tile [64d x 64k] in LDS, 128B rows, XOR-swizzled 16B slots
// (slot ^ (row&7)), staged linearly by global_load_lds from inverse-swizzled source.
// S^T = mfma(K, Q): lane holds 32 k-vals of one q-row. Q pre-scaled by 0.125*log2e at
// projection; p = exp2(st - m). Cross-half max/sum exchange via __shfl_xor (r2-proven;
// PLSWAP with same-value operands is unsafe — register coalescing degenerates it).
__global__ __launch_bounds__(256, 4)
void attn2(const unsigned short* __restrict__ Q, const unsigned short* __restrict__ K,
           const unsigned short* __restrict__ VT, unsigned short* __restrict__ O) {
    __shared__ unsigned short Kl[2][64 * 64];
    __shared__ unsigned short Vl[2][64 * 64];
    const int tid = threadIdx.x, wid = tid >> 6, lane = tid & 63;
    // XCD-aware decode: xcd = x&7 fixed by dispatch; qt varies fastest within an xcd,
    // so each XCD's resident blocks share few (b,h) K/V sets (fits per-XCD L2).
    const int x = blockIdx.x;
    const int i_ = x >> 3;
    const int qt = i_ & 15;
    const int bh = (x & 7) + 8 * (i_ >> 4);
    const int b = bh >> 4, h = bh & 15;
    const int q0 = qt * 128 + wid * 32;
    const int qcol = lane & 31, g = lane >> 5;
    const int rx7 = qcol & 7;   // (row&7) of the LDS rows this lane reads

    // Q as B-operand fragments: bq[ds] : q = qcol, d = ds*16 + g*8 + j  (pre-scaled)
    short8 bq[4];
    {
        const unsigned short* qp = Q + ((size_t)(b * 2048 + q0 + qcol)) * 1024 + h * 64 + g * 8;
#pragma unroll
        for (int ds = 0; ds < 4; ds++) bq[ds] = *(const short8*)(qp + ds * 16);
    }

    f32x16 oacc0, oacc1;
#pragma unroll
    for (int i = 0; i < 16; i++) { oacc0[i] = 0.f; oacc1[i] = 0.f; }
    float mrun = -1e30f, lrun = 0.f;

    // staging: 512 x 16B chunks per tile; chunk c = i*256 + tid -> LDS row c>>3, slot c&7.
    // source supplies global slot sg = (c&7) ^ ((c>>3)&7) so LDS[row][slot] = G[row][slot^row&7].
    const int srow = wid * 8 + (lane >> 3);
    const int sg = (lane & 7) ^ (lane >> 3);
    const unsigned short* gK0 = K + ((size_t)(b * 2048 + srow)) * 1024 + h * 64 + sg * 8;
    const unsigned short* gK1 = gK0 + (size_t)32 * 1024;
    const unsigned short* gV0 = VT + ((size_t)(b * 1024 + h * 64 + srow)) * 2048 + sg * 8;
    const unsigned short* gV1 = gV0 + (size_t)32 * 2048;

#define ATTN_STAGE(t_, bf_)                                                          \
    do {                                                                             \
        const size_t ko = (size_t)(t_) * 64 * 1024;                                  \
        const size_t vo = (size_t)(t_) * 64;                                         \
        gll16(gK0 + ko, (char*)Kl[bf_] + wid * 1024);                                \
        gll16(gK1 + ko, (char*)Kl[bf_] + 4096 + wid * 1024);                         \
        gll16(gV0 + vo, (char*)Vl[bf_] + wid * 1024);                                \
        gll16(gV1 + vo, (char*)Vl[bf_] + 4096 + wid * 1024);                         \
    } while (0)

    ATTN_STAGE(0, 0);

    for (int t = 0; t < 32; t++) {
        __syncthreads();                       // drains stage(t); all waves done with buf (t-1)
        if (t + 1 < 32) ATTN_STAGE(t + 1, (t + 1) & 1);
        const char* Kt = (const char*)Kl[t & 1];
        const char* Vt = (const char*)Vl[t & 1];

        // ---- S^T[k, q] = sum_d K[k,d] * Q[q,d]  (already in exp2-scaled units) ----
        f32x16 st0, st1;
#pragma unroll
        for (int i = 0; i < 16; i++) { st0[i] = 0.f; st1[i] = 0.f; }
        __builtin_amdgcn_s_setprio(1);
        {
            const char* kr0 = Kt + (qcol)*128;
            const char* kr1 = Kt + (32 + qcol) * 128;
#pragma unroll
            for (int ds = 0; ds < 4; ds++) {
                const int slot = ds * 2 + g;
                short8 a0 = *(const short8*)(kr0 + ((slot ^ rx7) << 4));
                short8 a1 = *(const short8*)(kr1 + ((slot ^ rx7) << 4));
                st0 = __builtin_amdgcn_mfma_f32_32x32x16_bf16(a0, bq[ds], st0, 0, 0, 0);
                st1 = __builtin_amdgcn_mfma_f32_32x32x16_bf16(a1, bq[ds], st1, 0, 0, 0);
            }
        }
        __builtin_amdgcn_s_setprio(0);

        // ---- tile max (tree + shfl cross-half exchange) ----
        float tm[8];
#pragma unroll
        for (int i = 0; i < 8; i++)
            tm[i] = fmaxf(fmaxf(st0[i], st0[i + 8]), fmaxf(st1[i], st1[i + 8]));
#pragma unroll
        for (int i = 0; i < 4; i++) tm[i] = fmaxf(tm[i], tm[i + 4]);
        float pm = fmaxf(fmaxf(tm[0], tm[1]), fmaxf(tm[2], tm[3]));
        pm = fmaxf(pm, __shfl_xor(pm, 32));

        // ---- online softmax, true running max (r2-verified numerics) ----
        const float nm = fmaxf(mrun, pm);
        const float corr = EXP2(mrun - nm);
        mrun = nm;

        // ---- p = exp2(st - m); sum (vector tree) ----
        f32x16 p0, p1;
#pragma unroll
        for (int i = 0; i < 16; i++) {
            p0[i] = EXP2(st0[i] - nm);
            p1[i] = EXP2(st1[i] - nm);
        }
        float ts[8];
#pragma unroll
        for (int i = 0; i < 8; i++) ts[i] = (p0[i] + p0[i + 8]) + (p1[i] + p1[i + 8]);
#pragma unroll
        for (int i = 0; i < 4; i++) ts[i] += ts[i + 4];
        float ps = (ts[0] + ts[1]) + (ts[2] + ts[3]);
        ps += __shfl_xor(ps, 32);
        lrun = lrun * corr + ps;
#pragma unroll
        for (int i = 0; i < 16; i++) { oacc0[i] *= corr; oacc1[i] *= corr; }

        // ---- P^T -> bf16 B-operand fragments (cvt_pk + permlane32_swap, T12) ----
        short8 pb[4];
        {
            unsigned int w[8];
#pragma unroll
            for (int p = 0; p < 8; p++) w[p] = cvtpk_bf16(p0[2 * p], p0[2 * p + 1]);
            PLSWAP(w[0], w[2]); PLSWAP(w[1], w[3]);
            PLSWAP(w[4], w[6]); PLSWAP(w[5], w[7]);
            uint4v lo = {w[0], w[1], w[2], w[3]};
            uint4v hi = {w[4], w[5], w[6], w[7]};
            pb[0] = __builtin_bit_cast(short8, lo);
            pb[1] = __builtin_bit_cast(short8, hi);
        }
        {
            unsigned int w[8];
#pragma unroll
            for (int p = 0; p < 8; p++) w[p] = cvtpk_bf16(p1[2 * p], p1[2 * p + 1]);
            PLSWAP(w[0], w[2]); PLSWAP(w[1], w[3]);
            PLSWAP(w[4], w[6]); PLSWAP(w[5], w[7]);
            uint4v lo = {w[0], w[1], w[2], w[3]};
            uint4v hi = {w[4], w[5], w[6], w[7]};
            pb[2] = __builtin_bit_cast(short8, lo);
            pb[3] = __builtin_bit_cast(short8, hi);
        }

        // ---- O^T[d, q] += sum_k V^T[d,k] * P^T[k,q] ----
        __builtin_amdgcn_s_setprio(1);
        {
            const char* vr0 = Vt + (qcol)*128;
            const char* vr1 = Vt + (32 + qcol) * 128;
#pragma unroll
            for (int kb = 0; kb < 4; kb++) {
                const int slot = kb * 2 + g;
                short8 a0 = *(const short8*)(vr0 + ((slot ^ rx7) << 4));
                short8 a1 = *(const short8*)(vr1 + ((slot ^ rx7) << 4));
                oacc0 = __builtin_amdgcn_mfma_f32_32x32x16_bf16(a0, pb[kb], oacc0, 0, 0, 0);
                oacc1 = __builtin_amdgcn_mfma_f32_32x32x16_bf16(a1, pb[kb], oacc1, 0, 0, 0);
            }
        }
        __builtin_amdgcn_s_setprio(0);
    }
#undef ATTN_STAGE

    // ---- epilogue: O[q][d] = O^T[d][q] / lrun ----
    const float inv = 1.f / lrun;
    unsigned short* orow = O + ((size_t)(b * 2048 + q0 + qcol)) * 1024 + h * 64;
#pragma unroll
    for (int dsub = 0; dsub < 2; dsub++)
#pragma unroll
        for (int q4 = 0; q4 < 4; q4++) {
            ushort4v pk;
#pragma unroll
            for (int rr = 0; rr < 4; rr++) {
                float v = (dsub == 0 ? oacc0[q4 * 4 + rr] : oacc1[q4 * 4 + rr]) * inv;
                pk[rr] = f2bf(v);
            }
            const int d0 = dsub * 32 + q4 * 8 + g * 4;
            *(ushort4v*)(orow + d0) = pk;
        }
}

// ---------------- launch ----------------
extern "C" void kernel_launch(void* const* d_in, const int* in_sizes, int n_in,
                              void* d_out, int out_size, void* d_ws, size_t ws_size,
                              hipStream_t stream) {
    const float* query = (const float*)d_in[0];
    const float* key_  = (const float*)d_in[1];
    const float* value = (const float*)d_in[2];
    const float* Wq = (const float*)d_in[3];
    const float* bq = (const float*)d_in[4];
    const float* Wk = (const float*)d_in[5];
    const float* bk = (const float*)d_in[6];
    const float* Wv = (const float*)d_in[7];
    const float* bv = (const float*)d_in[8];
    const float* Wo = (const float*)d_in[9];
    const float* bo = (const float*)d_in[10];

    char* ws = (char*)d_ws;
    unsigned short* Xbf = (unsigned short*)(ws);                    // 16 MB (attn out)
    unsigned short* Wqb = (unsigned short*)(ws + (16ull << 20));    // 2 MB
    unsigned short* Wkb = (unsigned short*)(ws + (18ull << 20));
    unsigned short* Wvb = (unsigned short*)(ws + (20ull << 20));
    unsigned short* Wob = (unsigned short*)(ws + (22ull << 20));
    unsigned short* Qb  = (unsigned short*)(ws + (24ull << 20));    // 16 MB
    unsigned short* Kb  = (unsigned short*)(ws + (40ull << 20));    // 16 MB
    unsigned short* VTb = (unsigned short*)(ws + (56ull << 20));    // 16 MB  (total 72 MB)

    cvtW<<<4096, 256, 0, stream>>>(Wq, Wk, Wv, Wo, Wqb, Wkb, Wvb, Wob);

    // projections: fp32 activations converted in-kernel (fused cvt, reg-staged A)
    gemm_nt<3, 1><<<512, 256, 0, stream>>>(query, Wqb, bq, Qb);   // Q pre-scaled for exp2
    gemm_nt<0, 1><<<512, 256, 0, stream>>>(key_, Wkb, bk, Kb);
    gemm_nt<1, 1><<<512, 256, 0, stream>>>(value, Wvb, bv, VTb);

    attn2<<<1024, 256, 0, stream>>>(Qb, Kb, VTb, Xbf);

    gemm_nt<2, 0><<<512, 256, 0, stream>>>(Xbf, Wob, bo, d_out);
}

// Round 7
// 202.777 us; speedup vs baseline: 1.9055x; 1.1697x over previous
//
#include <hip/hip_runtime.h>
#include <hip/hip_bf16.h>
#include <stdint.h>

// MultiHeadAttention on MI355X (gfx950), bf16 MFMA pipeline.
// B=4, S=2048, D=1024, H=16, Dh=64. M = B*S = 8192.

typedef __attribute__((ext_vector_type(4))) float f32x4;
typedef __attribute__((ext_vector_type(16))) float f32x16;
typedef __attribute__((ext_vector_type(8))) short short8;
typedef __attribute__((ext_vector_type(4))) unsigned short ushort4v;
typedef __attribute__((ext_vector_type(4))) unsigned int uint4v;

#define SCALE_Q 0.1803368801111f   // 0.125 * log2(e): softmax runs in exp2 domain
#define EXP2(x) __builtin_amdgcn_exp2f(x)

__device__ __forceinline__ unsigned short f2bf(float f) {
    union { float f; unsigned int u; } v; v.f = f;
    unsigned int u = v.u;
    u += 0x7FFFu + ((u >> 16) & 1u);   // RNE
    return (unsigned short)(u >> 16);
}

__device__ __forceinline__ void gll16(const void* g, void* l) {
    __builtin_amdgcn_global_load_lds(
        (const __attribute__((address_space(1))) void*)g,
        (__attribute__((address_space(3))) void*)l, 16, 0, 0);
}

// v_cvt_pk_bf16_f32: RNE (LLVM lowers fptrunc f32->bf16 to this on gfx950)
__device__ __forceinline__ unsigned int cvtpk_bf16(float lo, float hi) {
    unsigned int r;
    asm("v_cvt_pk_bf16_f32 %0, %1, %2" : "=v"(r) : "v"(lo), "v"(hi));
    return r;
}
// v_permlane32_swap_b32 a, b : a' = {a.lanes0-31, b.lanes0-31}, b' = {a.lanes32-63, b.lanes32-63}
// ONLY safe with provably-distinct operand values (same-value operands may be register-coalesced
// by the allocator, degenerating the swap — the r3/r4 accuracy bug).
#define PLSWAP(a, b) asm("v_permlane32_swap_b32 %0, %1" : "+v"(a), "+v"(b))

// ---------------- fp32 -> bf16 weight convert ----------------
__global__ __launch_bounds__(256) void cvtW(const float* __restrict__ s0, const float* __restrict__ s1,
                                            const float* __restrict__ s2, const float* __restrict__ s3,
                                            unsigned short* __restrict__ d0, unsigned short* __restrict__ d1,
                                            unsigned short* __restrict__ d2, unsigned short* __restrict__ d3) {
    int t = blockIdx.x >> 10;                       // 1024 blocks per 2^20-elem tensor
    const float* sp = (t == 0) ? s0 : (t == 1) ? s1 : (t == 2) ? s2 : s3;
    unsigned short* dp = (t == 0) ? d0 : (t == 1) ? d1 : (t == 2) ? d2 : d3;
    int j = ((blockIdx.x & 1023) * 256 + threadIdx.x) * 4;
    float4 v = *(const float4*)(sp + j);
    ushort4v o; o.x = f2bf(v.x); o.y = f2bf(v.y); o.z = f2bf(v.z); o.w = f2bf(v.w);
    *(ushort4v*)(dp + j) = o;
}

// ---------------- merged Q/K/V projection GEMM ----------------
// grid 1536: segment s = blockIdx>>9 in {0:Q, 1:K, 2:V}. A fp32 in-kernel cvt (reg-staged,
// prefetched one K-step ahead). Epilogue mode per segment (runtime, block-uniform):
// Q: bf16 * SCALE_Q; K: bf16; V: bf16 transposed VT[b][n][s].
// XCD-contiguous decode within segment (idx&7 = xcd owns 8 mtiles; A+B panels L2-resident).
__global__ __launch_bounds__(256, 2)
void proj3(const float* __restrict__ Aq, const float* __restrict__ Ak, const float* __restrict__ Av,
           const unsigned short* __restrict__ Wq, const unsigned short* __restrict__ Wk,
           const unsigned short* __restrict__ Wv,
           const float* __restrict__ bq, const float* __restrict__ bk, const float* __restrict__ bv,
           unsigned short* __restrict__ Cq, unsigned short* __restrict__ Ck,
           unsigned short* __restrict__ Cv) {
    __shared__ unsigned short As[128 * 32];
    __shared__ unsigned short Bs[128 * 32];
    const int tid = threadIdx.x;
    const int wid = tid >> 6, lane = tid & 63;
    const int seg = blockIdx.x >> 9, idx = blockIdx.x & 511;
    const float* Af = (seg == 0) ? Aq : (seg == 1) ? Ak : Av;
    const unsigned short* Bw = (seg == 0) ? Wq : (seg == 1) ? Wk : Wv;
    const float* bias = (seg == 0) ? bq : (seg == 1) ? bk : bv;
    unsigned short* C = (seg == 0) ? Cq : (seg == 1) ? Ck : Cv;

    const int xcd = idx & 7, j_ = idx >> 3;
    const int mtile = xcd * 8 + (j_ >> 3), ntile = j_ & 7;
    const int m0 = mtile * 128, n0 = ntile * 128;
    const int wm = (wid >> 1) * 64, wn = (wid & 1) * 64;

    f32x4 acc[4][4];
#pragma unroll
    for (int i = 0; i < 4; i++)
#pragma unroll
        for (int j = 0; j < 4; j++) acc[i][j] = f32x4{0.f, 0.f, 0.f, 0.f};

    const int srow = tid >> 2, scol = (tid & 3) * 8;
    const unsigned short* gB0 = Bw + (size_t)(n0 + srow) * 1024 + scol;
    const unsigned short* gB1 = Bw + (size_t)(n0 + 64 + srow) * 1024 + scol;
    char* lB0 = (char*)Bs + wid * 1024;
    char* lB1 = (char*)Bs + 4096 + wid * 1024;
    const float* gAf0 = Af + (size_t)(m0 + srow) * 1024 + scol;
    const float* gAf1 = Af + (size_t)(m0 + 64 + srow) * 1024 + scol;

    const int frow = lane & 15;
    const int fcol = (lane >> 4) * 16;   // byte offset of k-slice

    float4 p00 = *(const float4*)(gAf0);
    float4 p01 = *(const float4*)(gAf0 + 4);
    float4 p10 = *(const float4*)(gAf1);
    float4 p11 = *(const float4*)(gAf1 + 4);

    for (int k0 = 0; k0 < 1024; k0 += 32) {
        gll16(gB0 + k0, lB0);
        gll16(gB1 + k0, lB1);
        {
            uint4v wa = {cvtpk_bf16(p00.x, p00.y), cvtpk_bf16(p00.z, p00.w),
                         cvtpk_bf16(p01.x, p01.y), cvtpk_bf16(p01.z, p01.w)};
            uint4v wb = {cvtpk_bf16(p10.x, p10.y), cvtpk_bf16(p10.z, p10.w),
                         cvtpk_bf16(p11.x, p11.y), cvtpk_bf16(p11.z, p11.w)};
            *(uint4v*)((char*)As + tid * 16) = wa;
            *(uint4v*)((char*)As + 4096 + tid * 16) = wb;
        }
        __syncthreads();
        if (k0 + 32 < 1024) {    // prefetch next K-step under the MFMA phase
            p00 = *(const float4*)(gAf0 + k0 + 32);
            p01 = *(const float4*)(gAf0 + k0 + 36);
            p10 = *(const float4*)(gAf1 + k0 + 32);
            p11 = *(const float4*)(gAf1 + k0 + 36);
        }
        short8 af[4], bfr[4];
#pragma unroll
        for (int i = 0; i < 4; i++)
            af[i] = *(const short8*)((const char*)As + (wm + i * 16 + frow) * 64 + fcol);
#pragma unroll
        for (int j = 0; j < 4; j++)
            bfr[j] = *(const short8*)((const char*)Bs + (wn + j * 16 + frow) * 64 + fcol);
#pragma unroll
        for (int i = 0; i < 4; i++)
#pragma unroll
            for (int j = 0; j < 4; j++)
                acc[i][j] = __builtin_amdgcn_mfma_f32_16x16x32_bf16(af[i], bfr[j], acc[i][j], 0, 0, 0);
        __syncthreads();
    }

    // epilogue: C layout col = lane&15, row = (lane>>4)*4 + r  [m89-verified]
    if (seg == 2) {
        // V: transposed store VT[b][n][s]
#pragma unroll
        for (int i = 0; i < 4; i++)
#pragma unroll
            for (int j = 0; j < 4; j++) {
                const int n = n0 + wn + j * 16 + (lane & 15);
                const float bv_ = bias[n];
                const int mbase = m0 + wm + i * 16 + (lane >> 4) * 4;
                ushort4v pk;
#pragma unroll
                for (int r = 0; r < 4; r++) pk[r] = f2bf(acc[i][j][r] + bv_);
                const int b = mbase >> 11, s = mbase & 2047;
                *(ushort4v*)(C + ((size_t)b * 1024 + n) * 2048 + s) = pk;
            }
    } else {
        const float scl = (seg == 0) ? SCALE_Q : 1.0f;
#pragma unroll
        for (int i = 0; i < 4; i++)
#pragma unroll
            for (int j = 0; j < 4; j++) {
                const int n = n0 + wn + j * 16 + (lane & 15);
                const float bv_ = bias[n];
#pragma unroll
                for (int r = 0; r < 4; r++) {
                    const int m = m0 + wm + i * 16 + (lane >> 4) * 4 + r;
                    C[(size_t)m * 1024 + n] = f2bf((acc[i][j][r] + bv_) * scl);
                }
            }
    }
}

// ---------------- output GEMM: C[m,n] = sum_k A[m,k]*W[n,k] + bias[n], f32 out ----------------
__global__ __launch_bounds__(256, 2)
void gemm_out(const unsigned short* __restrict__ A, const unsigned short* __restrict__ Bw,
              const float* __restrict__ bias, float* __restrict__ C) {
    __shared__ unsigned short As[128 * 32];
    __shared__ unsigned short Bs[128 * 32];
    const int tid = threadIdx.x;
    const int wid = tid >> 6, lane = tid & 63;
    const int xcd = blockIdx.x & 7, j_ = blockIdx.x >> 3;
    const int mtile = xcd * 8 + (j_ >> 3), ntile = j_ & 7;
    const int m0 = mtile * 128, n0 = ntile * 128;
    const int wm = (wid >> 1) * 64, wn = (wid & 1) * 64;

    f32x4 acc[4][4];
#pragma unroll
    for (int i = 0; i < 4; i++)
#pragma unroll
        for (int j = 0; j < 4; j++) acc[i][j] = f32x4{0.f, 0.f, 0.f, 0.f};

    const int srow = tid >> 2, scol = (tid & 3) * 8;
    const unsigned short* gA0 = A + (size_t)(m0 + srow) * 1024 + scol;
    const unsigned short* gA1 = A + (size_t)(m0 + 64 + srow) * 1024 + scol;
    const unsigned short* gB0 = Bw + (size_t)(n0 + srow) * 1024 + scol;
    const unsigned short* gB1 = Bw + (size_t)(n0 + 64 + srow) * 1024 + scol;
    char* lA0 = (char*)As + wid * 1024;
    char* lA1 = (char*)As + 4096 + wid * 1024;
    char* lB0 = (char*)Bs + wid * 1024;
    char* lB1 = (char*)Bs + 4096 + wid * 1024;

    const int frow = lane & 15;
    const int fcol = (lane >> 4) * 16;

    for (int k0 = 0; k0 < 1024; k0 += 32) {
        gll16(gA0 + k0, lA0);
        gll16(gA1 + k0, lA1);
        gll16(gB0 + k0, lB0);
        gll16(gB1 + k0, lB1);
        __syncthreads();
        short8 af[4], bfr[4];
#pragma unroll
        for (int i = 0; i < 4; i++)
            af[i] = *(const short8*)((const char*)As + (wm + i * 16 + frow) * 64 + fcol);
#pragma unroll
        for (int j = 0; j < 4; j++)
            bfr[j] = *(const short8*)((const char*)Bs + (wn + j * 16 + frow) * 64 + fcol);
#pragma unroll
        for (int i = 0; i < 4; i++)
#pragma unroll
            for (int j = 0; j < 4; j++)
                acc[i][j] = __builtin_amdgcn_mfma_f32_16x16x32_bf16(af[i], bfr[j], acc[i][j], 0, 0, 0);
        __syncthreads();
    }

#pragma unroll
    for (int i = 0; i < 4; i++)
#pragma unroll
        for (int j = 0; j < 4; j++) {
            const int n = n0 + wn + j * 16 + (lane & 15);
            const float bv = bias[n];
#pragma unroll
            for (int r = 0; r < 4; r++) {
                const int m = m0 + wm + i * 16 + (lane >> 4) * 4 + r;
                C[(size_t)m * 1024 + n] = acc[i][j][r] + bv;
            }
        }
}

// ---------------- flash attention v6: + T13 defer-max (exp2 domain, THR=8) ----------------
// block 256 = 4 warps; warp owns 32 q-rows -> block = 128 q rows. grid = 1024 (XCD-swizzled).
// K tile [64k x 64d], V^T tile [64d x 64k] in LDS, 128B rows, XOR-swizzled 16B slots
// (slot ^ (row&7)), staged linearly by global_load_lds from inverse-swizzled source.
// S^T = mfma(K, Q): lane holds 32 k-vals of one q-row. Q pre-scaled by 0.125*log2e at
// projection; p = exp2(st - m), P <= 2^8 when deferred (scale cancels in normalize).
__global__ __launch_bounds__(256, 4)
void attn2(const unsigned short* __restrict__ Q, const unsigned short* __restrict__ K,
           const unsigned short* __restrict__ VT, unsigned short* __restrict__ O) {
    __shared__ unsigned short Kl[2][64 * 64];
    __shared__ unsigned short Vl[2][64 * 64];
    const int tid = threadIdx.x, wid = tid >> 6, lane = tid & 63;
    const int x = blockIdx.x;
    const int i_ = x >> 3;
    const int qt = i_ & 15;
    const int bh = (x & 7) + 8 * (i_ >> 4);
    const int b = bh >> 4, h = bh & 15;
    const int q0 = qt * 128 + wid * 32;
    const int qcol = lane & 31, g = lane >> 5;
    const int rx7 = qcol & 7;   // (row&7) of the LDS rows this lane reads

    // Q as B-operand fragments: bq[ds] : q = qcol, d = ds*16 + g*8 + j  (pre-scaled)
    short8 bq[4];
    {
        const unsigned short* qp = Q + ((size_t)(b * 2048 + q0 + qcol)) * 1024 + h * 64 + g * 8;
#pragma unroll
        for (int ds = 0; ds < 4; ds++) bq[ds] = *(const short8*)(qp + ds * 16);
    }

    f32x16 oacc0, oacc1;
#pragma unroll
    for (int i = 0; i < 16; i++) { oacc0[i] = 0.f; oacc1[i] = 0.f; }
    float mrun = -1e30f, lrun = 0.f;

    const int srow = wid * 8 + (lane >> 3);
    const int sg = (lane & 7) ^ (lane >> 3);
    const unsigned short* gK0 = K + ((size_t)(b * 2048 + srow)) * 1024 + h * 64 + sg * 8;
    const unsigned short* gK1 = gK0 + (size_t)32 * 1024;
    const unsigned short* gV0 = VT + ((size_t)(b * 1024 + h * 64 + srow)) * 2048 + sg * 8;
    const unsigned short* gV1 = gV0 + (size_t)32 * 2048;

#define ATTN_STAGE(t_, bf_)                                                          \
    do {                                                                             \
        const size_t ko = (size_t)(t_) * 64 * 1024;                                  \
        const size_t vo = (size_t)(t_) * 64;                                         \
        gll16(gK0 + ko, (char*)Kl[bf_] + wid * 1024);                                \
        gll16(gK1 + ko, (char*)Kl[bf_] + 4096 + wid * 1024);                         \
        gll16(gV0 + vo, (char*)Vl[bf_] + wid * 1024);                                \
        gll16(gV1 + vo, (char*)Vl[bf_] + 4096 + wid * 1024);                         \
    } while (0)

    ATTN_STAGE(0, 0);

    for (int t = 0; t < 32; t++) {
        __syncthreads();                       // drains stage(t); all waves done with buf (t-1)
        if (t + 1 < 32) ATTN_STAGE(t + 1, (t + 1) & 1);
        const char* Kt = (const char*)Kl[t & 1];
        const char* Vt = (const char*)Vl[t & 1];

        // ---- S^T[k, q] = sum_d K[k,d] * Q[q,d]  (already in exp2-scaled units) ----
        f32x16 st0, st1;
#pragma unroll
        for (int i = 0; i < 16; i++) { st0[i] = 0.f; st1[i] = 0.f; }
        __builtin_amdgcn_s_setprio(1);
        {
            const char* kr0 = Kt + (qcol)*128;
            const char* kr1 = Kt + (32 + qcol) * 128;
#pragma unroll
            for (int ds = 0; ds < 4; ds++) {
                const int slot = ds * 2 + g;
                short8 a0 = *(const short8*)(kr0 + ((slot ^ rx7) << 4));
                short8 a1 = *(const short8*)(kr1 + ((slot ^ rx7) << 4));
                st0 = __builtin_amdgcn_mfma_f32_32x32x16_bf16(a0, bq[ds], st0, 0, 0, 0);
                st1 = __builtin_amdgcn_mfma_f32_32x32x16_bf16(a1, bq[ds], st1, 0, 0, 0);
            }
        }
        __builtin_amdgcn_s_setprio(0);

        // ---- tile max (tree + shfl cross-half exchange) ----
        float tm[8];
#pragma unroll
        for (int i = 0; i < 8; i++)
            tm[i] = fmaxf(fmaxf(st0[i], st0[i + 8]), fmaxf(st1[i], st1[i + 8]));
#pragma unroll
        for (int i = 0; i < 4; i++) tm[i] = fmaxf(tm[i], tm[i + 4]);
        float pm = fmaxf(fmaxf(tm[0], tm[1]), fmaxf(tm[2], tm[3]));
        pm = fmaxf(pm, __shfl_xor(pm, 32));

        // ---- T13 defer-max (exp2 domain): rescale only when max grew past THR=8 ----
        // Deferred P <= 2^8; lrun and oacc share the 2^(-mrun) scale -> cancels at normalize.
        if (!__all(pm <= mrun + 8.f)) {
            const float nm = fmaxf(mrun, pm);
            const float corr = EXP2(mrun - nm);
            mrun = nm;
            lrun *= corr;
#pragma unroll
            for (int i = 0; i < 16; i++) { oacc0[i] *= corr; oacc1[i] *= corr; }
        }

        // ---- p = exp2(st - m); sum (vector tree) ----
        f32x16 p0, p1;
#pragma unroll
        for (int i = 0; i < 16; i++) {
            p0[i] = EXP2(st0[i] - mrun);
            p1[i] = EXP2(st1[i] - mrun);
        }
        float ts[8];
#pragma unroll
        for (int i = 0; i < 8; i++) ts[i] = (p0[i] + p0[i + 8]) + (p1[i] + p1[i + 8]);
#pragma unroll
        for (int i = 0; i < 4; i++) ts[i] += ts[i + 4];
        float ps = (ts[0] + ts[1]) + (ts[2] + ts[3]);
        ps += __shfl_xor(ps, 32);
        lrun += ps;

        // ---- P^T -> bf16 B-operand fragments (cvt_pk + permlane32_swap, T12) ----
        short8 pb[4];
        {
            unsigned int w[8];
#pragma unroll
            for (int p = 0; p < 8; p++) w[p] = cvtpk_bf16(p0[2 * p], p0[2 * p + 1]);
            PLSWAP(w[0], w[2]); PLSWAP(w[1], w[3]);
            PLSWAP(w[4], w[6]); PLSWAP(w[5], w[7]);
            uint4v lo = {w[0], w[1], w[2], w[3]};
            uint4v hi = {w[4], w[5], w[6], w[7]};
            pb[0] = __builtin_bit_cast(short8, lo);
            pb[1] = __builtin_bit_cast(short8, hi);
        }
        {
            unsigned int w[8];
#pragma unroll
            for (int p = 0; p < 8; p++) w[p] = cvtpk_bf16(p1[2 * p], p1[2 * p + 1]);
            PLSWAP(w[0], w[2]); PLSWAP(w[1], w[3]);
            PLSWAP(w[4], w[6]); PLSWAP(w[5], w[7]);
            uint4v lo = {w[0], w[1], w[2], w[3]};
            uint4v hi = {w[4], w[5], w[6], w[7]};
            pb[2] = __builtin_bit_cast(short8, lo);
            pb[3] = __builtin_bit_cast(short8, hi);
        }

        // ---- O^T[d, q] += sum_k V^T[d,k] * P^T[k,q] ----
        __builtin_amdgcn_s_setprio(1);
        {
            const char* vr0 = Vt + (qcol)*128;
            const char* vr1 = Vt + (32 + qcol) * 128;
#pragma unroll
            for (int kb = 0; kb < 4; kb++) {
                const int slot = kb * 2 + g;
                short8 a0 = *(const short8*)(vr0 + ((slot ^ rx7) << 4));
                short8 a1 = *(const short8*)(vr1 + ((slot ^ rx7) << 4));
                oacc0 = __builtin_amdgcn_mfma_f32_32x32x16_bf16(a0, pb[kb], oacc0, 0, 0, 0);
                oacc1 = __builtin_amdgcn_mfma_f32_32x32x16_bf16(a1, pb[kb], oacc1, 0, 0, 0);
            }
        }
        __builtin_amdgcn_s_setprio(0);
    }
#undef ATTN_STAGE

    // ---- epilogue: O[q][d] = O^T[d][q] / lrun ----
    const float inv = 1.f / lrun;
    unsigned short* orow = O + ((size_t)(b * 2048 + q0 + qcol)) * 1024 + h * 64;
#pragma unroll
    for (int dsub = 0; dsub < 2; dsub++)
#pragma unroll
        for (int q4 = 0; q4 < 4; q4++) {
            ushort4v pk;
#pragma unroll
            for (int rr = 0; rr < 4; rr++) {
                float v = (dsub == 0 ? oacc0[q4 * 4 + rr] : oacc1[q4 * 4 + rr]) * inv;
                pk[rr] = f2bf(v);
            }
            const int d0 = dsub * 32 + q4 * 8 + g * 4;
            *(ushort4v*)(orow + d0) = pk;
        }
}

// ---------------- launch ----------------
extern "C" void kernel_launch(void* const* d_in, const int* in_sizes, int n_in,
                              void* d_out, int out_size, void* d_ws, size_t ws_size,
                              hipStream_t stream) {
    const float* query = (const float*)d_in[0];
    const float* key_  = (const float*)d_in[1];
    const float* value = (const float*)d_in[2];
    const float* Wq = (const float*)d_in[3];
    const float* bq = (const float*)d_in[4];
    const float* Wk = (const float*)d_in[5];
    const float* bk = (const float*)d_in[6];
    const float* Wv = (const float*)d_in[7];
    const float* bv = (const float*)d_in[8];
    const float* Wo = (const float*)d_in[9];
    const float* bo = (const float*)d_in[10];

    char* ws = (char*)d_ws;
    unsigned short* Xbf = (unsigned short*)(ws);                    // 16 MB (attn out)
    unsigned short* Wqb = (unsigned short*)(ws + (16ull << 20));    // 2 MB
    unsigned short* Wkb = (unsigned short*)(ws + (18ull << 20));
    unsigned short* Wvb = (unsigned short*)(ws + (20ull << 20));
    unsigned short* Wob = (unsigned short*)(ws + (22ull << 20));
    unsigned short* Qb  = (unsigned short*)(ws + (24ull << 20));    // 16 MB
    unsigned short* Kb  = (unsigned short*)(ws + (40ull << 20));    // 16 MB
    unsigned short* VTb = (unsigned short*)(ws + (56ull << 20));    // 16 MB  (total 72 MB)

    cvtW<<<4096, 256, 0, stream>>>(Wq, Wk, Wv, Wo, Wqb, Wkb, Wvb, Wob);

    // merged Q/K/V projections (fp32 A converted in-kernel, Q pre-scaled for exp2 softmax)
    proj3<<<1536, 256, 0, stream>>>(query, key_, value, Wqb, Wkb, Wvb,
                                    bq, bk, bv, Qb, Kb, VTb);

    attn2<<<1024, 256, 0, stream>>>(Qb, Kb, VTb, Xbf);

    gemm_out<<<512, 256, 0, stream>>>(Xbf, Wob, bo, (float*)d_out);
}

// Round 8
// 201.940 us; speedup vs baseline: 1.9134x; 1.0041x over previous
//
#include <hip/hip_runtime.h>
#include <hip/hip_bf16.h>
#include <stdint.h>

// MultiHeadAttention on MI355X (gfx950), bf16 MFMA pipeline.
// B=4, S=2048, D=1024, H=16, Dh=64. M = B*S = 8192.

typedef __attribute__((ext_vector_type(4))) float f32x4;
typedef __attribute__((ext_vector_type(16))) float f32x16;
typedef __attribute__((ext_vector_type(8))) short short8;
typedef __attribute__((ext_vector_type(4))) unsigned short ushort4v;
typedef __attribute__((ext_vector_type(4))) unsigned int uint4v;

#define SCALE_Q 0.1803368801111f   // 0.125 * log2(e): softmax runs in exp2 domain
#define EXP2(x) __builtin_amdgcn_exp2f(x)

__device__ __forceinline__ unsigned short f2bf(float f) {
    union { float f; unsigned int u; } v; v.f = f;
    unsigned int u = v.u;
    u += 0x7FFFu + ((u >> 16) & 1u);   // RNE
    return (unsigned short)(u >> 16);
}

__device__ __forceinline__ void gll16(const void* g, void* l) {
    __builtin_amdgcn_global_load_lds(
        (const __attribute__((address_space(1))) void*)g,
        (__attribute__((address_space(3))) void*)l, 16, 0, 0);
}

// v_cvt_pk_bf16_f32: RNE (LLVM lowers fptrunc f32->bf16 to this on gfx950)
__device__ __forceinline__ unsigned int cvtpk_bf16(float lo, float hi) {
    unsigned int r;
    asm("v_cvt_pk_bf16_f32 %0, %1, %2" : "=v"(r) : "v"(lo), "v"(hi));
    return r;
}
// v_permlane32_swap_b32 a, b : a' = {a.lanes0-31, b.lanes0-31}, b' = {a.lanes32-63, b.lanes32-63}
// ONLY safe with provably-distinct operand values (same-value operands may be register-coalesced
// by the allocator, degenerating the swap — the r3/r4 accuracy bug).
#define PLSWAP(a, b) asm("v_permlane32_swap_b32 %0, %1" : "+v"(a), "+v"(b))

// ---------------- fp32 -> bf16 weight convert ----------------
__global__ __launch_bounds__(256) void cvtW(const float* __restrict__ s0, const float* __restrict__ s1,
                                            const float* __restrict__ s2, const float* __restrict__ s3,
                                            unsigned short* __restrict__ d0, unsigned short* __restrict__ d1,
                                            unsigned short* __restrict__ d2, unsigned short* __restrict__ d3) {
    int t = blockIdx.x >> 10;                       // 1024 blocks per 2^20-elem tensor
    const float* sp = (t == 0) ? s0 : (t == 1) ? s1 : (t == 2) ? s2 : s3;
    unsigned short* dp = (t == 0) ? d0 : (t == 1) ? d1 : (t == 2) ? d2 : d3;
    int j = ((blockIdx.x & 1023) * 256 + threadIdx.x) * 4;
    float4 v = *(const float4*)(sp + j);
    ushort4v o; o.x = f2bf(v.x); o.y = f2bf(v.y); o.z = f2bf(v.z); o.w = f2bf(v.w);
    *(ushort4v*)(dp + j) = o;
}

// ---------------- merged Q/K/V projection GEMM (double-buffered, 1 barrier/K-step) ----------------
// grid 1536: segment s = blockIdx>>9 in {0:Q, 1:K, 2:V}. A fp32 converted in-kernel.
// Schedule per K-step t: {issue gll16 B(t+1) -> buf^1; cvt+ds_write A(t+1) -> buf^1 (regs
// prefetched at t-1); issue fp32 loads A(t+2); ds_read buf; 16 MFMA; barrier}. Staging has a
// full iteration to land (vs issue-and-drain-same-phase, the r7 112us latency stall).
__global__ __launch_bounds__(256, 2)
void proj3(const float* __restrict__ Aq, const float* __restrict__ Ak, const float* __restrict__ Av,
           const unsigned short* __restrict__ Wq, const unsigned short* __restrict__ Wk,
           const unsigned short* __restrict__ Wv,
           const float* __restrict__ bq, const float* __restrict__ bk, const float* __restrict__ bv,
           unsigned short* __restrict__ Cq, unsigned short* __restrict__ Ck,
           unsigned short* __restrict__ Cv) {
    __shared__ unsigned short As[2][128 * 32];
    __shared__ unsigned short Bs[2][128 * 32];
    const int tid = threadIdx.x;
    const int wid = tid >> 6, lane = tid & 63;
    const int seg = blockIdx.x >> 9, idx = blockIdx.x & 511;
    const float* Af = (seg == 0) ? Aq : (seg == 1) ? Ak : Av;
    const unsigned short* Bw = (seg == 0) ? Wq : (seg == 1) ? Wk : Wv;
    const float* bias = (seg == 0) ? bq : (seg == 1) ? bk : bv;
    unsigned short* C = (seg == 0) ? Cq : (seg == 1) ? Ck : Cv;

    const int xcd = idx & 7, j_ = idx >> 3;
    const int mtile = xcd * 8 + (j_ >> 3), ntile = j_ & 7;
    const int m0 = mtile * 128, n0 = ntile * 128;
    const int wm = (wid >> 1) * 64, wn = (wid & 1) * 64;

    f32x4 acc[4][4];
#pragma unroll
    for (int i = 0; i < 4; i++)
#pragma unroll
        for (int j = 0; j < 4; j++) acc[i][j] = f32x4{0.f, 0.f, 0.f, 0.f};

    const int srow = tid >> 2, scol = (tid & 3) * 8;
    const unsigned short* gB0 = Bw + (size_t)(n0 + srow) * 1024 + scol;
    const unsigned short* gB1 = Bw + (size_t)(n0 + 64 + srow) * 1024 + scol;
    const float* gAf0 = Af + (size_t)(m0 + srow) * 1024 + scol;
    const float* gAf1 = Af + (size_t)(m0 + 64 + srow) * 1024 + scol;

    const int frow = lane & 15;
    const int fcol = (lane >> 4) * 16;   // byte offset of k-slice

    // prologue: A(0) regs -> cvt -> buf0; gll16 B(0) -> buf0; prefetch A(1); barrier
    float4 p00 = *(const float4*)(gAf0);
    float4 p01 = *(const float4*)(gAf0 + 4);
    float4 p10 = *(const float4*)(gAf1);
    float4 p11 = *(const float4*)(gAf1 + 4);
    gll16(gB0, (char*)Bs[0] + wid * 1024);
    gll16(gB1, (char*)Bs[0] + 4096 + wid * 1024);
    {
        uint4v wa = {cvtpk_bf16(p00.x, p00.y), cvtpk_bf16(p00.z, p00.w),
                     cvtpk_bf16(p01.x, p01.y), cvtpk_bf16(p01.z, p01.w)};
        uint4v wb = {cvtpk_bf16(p10.x, p10.y), cvtpk_bf16(p10.z, p10.w),
                     cvtpk_bf16(p11.x, p11.y), cvtpk_bf16(p11.z, p11.w)};
        *(uint4v*)((char*)As[0] + tid * 16) = wa;
        *(uint4v*)((char*)As[0] + 4096 + tid * 16) = wb;
    }
    p00 = *(const float4*)(gAf0 + 32);
    p01 = *(const float4*)(gAf0 + 36);
    p10 = *(const float4*)(gAf1 + 32);
    p11 = *(const float4*)(gAf1 + 36);
    __syncthreads();

    int c = 0;
    for (int k0 = 0; k0 < 1024; k0 += 32) {
        const int kn = k0 + 32;
        if (kn < 1024) {
            gll16(gB0 + kn, (char*)Bs[c ^ 1] + wid * 1024);
            gll16(gB1 + kn, (char*)Bs[c ^ 1] + 4096 + wid * 1024);
            uint4v wa = {cvtpk_bf16(p00.x, p00.y), cvtpk_bf16(p00.z, p00.w),
                         cvtpk_bf16(p01.x, p01.y), cvtpk_bf16(p01.z, p01.w)};
            uint4v wb = {cvtpk_bf16(p10.x, p10.y), cvtpk_bf16(p10.z, p10.w),
                         cvtpk_bf16(p11.x, p11.y), cvtpk_bf16(p11.z, p11.w)};
            *(uint4v*)((char*)As[c ^ 1] + tid * 16) = wa;
            *(uint4v*)((char*)As[c ^ 1] + 4096 + tid * 16) = wb;
            if (kn + 32 < 1024) {    // prefetch A(t+2), consumed next iteration
                p00 = *(const float4*)(gAf0 + kn + 32);
                p01 = *(const float4*)(gAf0 + kn + 36);
                p10 = *(const float4*)(gAf1 + kn + 32);
                p11 = *(const float4*)(gAf1 + kn + 36);
            }
        }
        short8 af[4], bfr[4];
#pragma unroll
        for (int i = 0; i < 4; i++)
            af[i] = *(const short8*)((const char*)As[c] + (wm + i * 16 + frow) * 64 + fcol);
#pragma unroll
        for (int j = 0; j < 4; j++)
            bfr[j] = *(const short8*)((const char*)Bs[c] + (wn + j * 16 + frow) * 64 + fcol);
#pragma unroll
        for (int i = 0; i < 4; i++)
#pragma unroll
            for (int j = 0; j < 4; j++)
                acc[i][j] = __builtin_amdgcn_mfma_f32_16x16x32_bf16(af[i], bfr[j], acc[i][j], 0, 0, 0);
        __syncthreads();
        c ^= 1;
    }

    // epilogue: C layout col = lane&15, row = (lane>>4)*4 + r  [m89-verified]
    if (seg == 2) {
        // V: transposed store VT[b][n][s]
#pragma unroll
        for (int i = 0; i < 4; i++)
#pragma unroll
            for (int j = 0; j < 4; j++) {
                const int n = n0 + wn + j * 16 + (lane & 15);
                const float bv_ = bias[n];
                const int mbase = m0 + wm + i * 16 + (lane >> 4) * 4;
                ushort4v pk;
#pragma unroll
                for (int r = 0; r < 4; r++) pk[r] = f2bf(acc[i][j][r] + bv_);
                const int b = mbase >> 11, s = mbase & 2047;
                *(ushort4v*)(C + ((size_t)b * 1024 + n) * 2048 + s) = pk;
            }
    } else {
        const float scl = (seg == 0) ? SCALE_Q : 1.0f;
#pragma unroll
        for (int i = 0; i < 4; i++)
#pragma unroll
            for (int j = 0; j < 4; j++) {
                const int n = n0 + wn + j * 16 + (lane & 15);
                const float bv_ = bias[n];
#pragma unroll
                for (int r = 0; r < 4; r++) {
                    const int m = m0 + wm + i * 16 + (lane >> 4) * 4 + r;
                    C[(size_t)m * 1024 + n] = f2bf((acc[i][j][r] + bv_) * scl);
                }
            }
    }
}

// ---------------- output GEMM (double-buffered, 1 barrier/K-step), f32 out ----------------
__global__ __launch_bounds__(256, 2)
void gemm_out(const unsigned short* __restrict__ A, const unsigned short* __restrict__ Bw,
              const float* __restrict__ bias, float* __restrict__ C) {
    __shared__ unsigned short As[2][128 * 32];
    __shared__ unsigned short Bs[2][128 * 32];
    const int tid = threadIdx.x;
    const int wid = tid >> 6, lane = tid & 63;
    const int xcd = blockIdx.x & 7, j_ = blockIdx.x >> 3;
    const int mtile = xcd * 8 + (j_ >> 3), ntile = j_ & 7;
    const int m0 = mtile * 128, n0 = ntile * 128;
    const int wm = (wid >> 1) * 64, wn = (wid & 1) * 64;

    f32x4 acc[4][4];
#pragma unroll
    for (int i = 0; i < 4; i++)
#pragma unroll
        for (int j = 0; j < 4; j++) acc[i][j] = f32x4{0.f, 0.f, 0.f, 0.f};

    const int srow = tid >> 2, scol = (tid & 3) * 8;
    const unsigned short* gA0 = A + (size_t)(m0 + srow) * 1024 + scol;
    const unsigned short* gA1 = A + (size_t)(m0 + 64 + srow) * 1024 + scol;
    const unsigned short* gB0 = Bw + (size_t)(n0 + srow) * 1024 + scol;
    const unsigned short* gB1 = Bw + (size_t)(n0 + 64 + srow) * 1024 + scol;

    const int frow = lane & 15;
    const int fcol = (lane >> 4) * 16;

    // prologue: stage k0=0 into buf0
    gll16(gA0, (char*)As[0] + wid * 1024);
    gll16(gA1, (char*)As[0] + 4096 + wid * 1024);
    gll16(gB0, (char*)Bs[0] + wid * 1024);
    gll16(gB1, (char*)Bs[0] + 4096 + wid * 1024);
    __syncthreads();

    int c = 0;
    for (int k0 = 0; k0 < 1024; k0 += 32) {
        const int kn = k0 + 32;
        if (kn < 1024) {
            gll16(gA0 + kn, (char*)As[c ^ 1] + wid * 1024);
            gll16(gA1 + kn, (char*)As[c ^ 1] + 4096 + wid * 1024);
            gll16(gB0 + kn, (char*)Bs[c ^ 1] + wid * 1024);
            gll16(gB1 + kn, (char*)Bs[c ^ 1] + 4096 + wid * 1024);
        }
        short8 af[4], bfr[4];
#pragma unroll
        for (int i = 0; i < 4; i++)
            af[i] = *(const short8*)((const char*)As[c] + (wm + i * 16 + frow) * 64 + fcol);
#pragma unroll
        for (int j = 0; j < 4; j++)
            bfr[j] = *(const short8*)((const char*)Bs[c] + (wn + j * 16 + frow) * 64 + fcol);
#pragma unroll
        for (int i = 0; i < 4; i++)
#pragma unroll
            for (int j = 0; j < 4; j++)
                acc[i][j] = __builtin_amdgcn_mfma_f32_16x16x32_bf16(af[i], bfr[j], acc[i][j], 0, 0, 0);
        __syncthreads();
        c ^= 1;
    }

#pragma unroll
    for (int i = 0; i < 4; i++)
#pragma unroll
        for (int j = 0; j < 4; j++) {
            const int n = n0 + wn + j * 16 + (lane & 15);
            const float bv = bias[n];
#pragma unroll
            for (int r = 0; r < 4; r++) {
                const int m = m0 + wm + i * 16 + (lane >> 4) * 4 + r;
                C[(size_t)m * 1024 + n] = acc[i][j][r] + bv;
            }
        }
}

// ---------------- flash attention v6: + T13 defer-max (exp2 domain, THR=8) ----------------
// block 256 = 4 warps; warp owns 32 q-rows -> block = 128 q rows. grid = 1024 (XCD-swizzled).
// K tile [64k x 64d], V^T tile [64d x 64k] in LDS, 128B rows, XOR-swizzled 16B slots
// (slot ^ (row&7)), staged linearly by global_load_lds from inverse-swizzled source.
// S^T = mfma(K, Q): lane holds 32 k-vals of one q-row. Q pre-scaled by 0.125*log2e at
// projection; p = exp2(st - m), P <= 2^8 when deferred (scale cancels in normalize).
__global__ __launch_bounds__(256, 4)
void attn2(const unsigned short* __restrict__ Q, const unsigned short* __restrict__ K,
           const unsigned short* __restrict__ VT, unsigned short* __restrict__ O) {
    __shared__ unsigned short Kl[2][64 * 64];
    __shared__ unsigned short Vl[2][64 * 64];
    const int tid = threadIdx.x, wid = tid >> 6, lane = tid & 63;
    const int x = blockIdx.x;
    const int i_ = x >> 3;
    const int qt = i_ & 15;
    const int bh = (x & 7) + 8 * (i_ >> 4);
    const int b = bh >> 4, h = bh & 15;
    const int q0 = qt * 128 + wid * 32;
    const int qcol = lane & 31, g = lane >> 5;
    const int rx7 = qcol & 7;   // (row&7) of the LDS rows this lane reads

    // Q as B-operand fragments: bq[ds] : q = qcol, d = ds*16 + g*8 + j  (pre-scaled)
    short8 bq[4];
    {
        const unsigned short* qp = Q + ((size_t)(b * 2048 + q0 + qcol)) * 1024 + h * 64 + g * 8;
#pragma unroll
        for (int ds = 0; ds < 4; ds++) bq[ds] = *(const short8*)(qp + ds * 16);
    }

    f32x16 oacc0, oacc1;
#pragma unroll
    for (int i = 0; i < 16; i++) { oacc0[i] = 0.f; oacc1[i] = 0.f; }
    float mrun = -1e30f, lrun = 0.f;

    const int srow = wid * 8 + (lane >> 3);
    const int sg = (lane & 7) ^ (lane >> 3);
    const unsigned short* gK0 = K + ((size_t)(b * 2048 + srow)) * 1024 + h * 64 + sg * 8;
    const unsigned short* gK1 = gK0 + (size_t)32 * 1024;
    const unsigned short* gV0 = VT + ((size_t)(b * 1024 + h * 64 + srow)) * 2048 + sg * 8;
    const unsigned short* gV1 = gV0 + (size_t)32 * 2048;

#define ATTN_STAGE(t_, bf_)                                                          \
    do {                                                                             \
        const size_t ko = (size_t)(t_) * 64 * 1024;                                  \
        const size_t vo = (size_t)(t_) * 64;                                         \
        gll16(gK0 + ko, (char*)Kl[bf_] + wid * 1024);                                \
        gll16(gK1 + ko, (char*)Kl[bf_] + 4096 + wid * 1024);                         \
        gll16(gV0 + vo, (char*)Vl[bf_] + wid * 1024);                                \
        gll16(gV1 + vo, (char*)Vl[bf_] + 4096 + wid * 1024);                         \
    } while (0)

    ATTN_STAGE(0, 0);

    for (int t = 0; t < 32; t++) {
        __syncthreads();                       // drains stage(t); all waves done with buf (t-1)
        if (t + 1 < 32) ATTN_STAGE(t + 1, (t + 1) & 1);
        const char* Kt = (const char*)Kl[t & 1];
        const char* Vt = (const char*)Vl[t & 1];

        // ---- S^T[k, q] = sum_d K[k,d] * Q[q,d]  (already in exp2-scaled units) ----
        f32x16 st0, st1;
#pragma unroll
        for (int i = 0; i < 16; i++) { st0[i] = 0.f; st1[i] = 0.f; }
        __builtin_amdgcn_s_setprio(1);
        {
            const char* kr0 = Kt + (qcol)*128;
            const char* kr1 = Kt + (32 + qcol) * 128;
#pragma unroll
            for (int ds = 0; ds < 4; ds++) {
                const int slot = ds * 2 + g;
                short8 a0 = *(const short8*)(kr0 + ((slot ^ rx7) << 4));
                short8 a1 = *(const short8*)(kr1 + ((slot ^ rx7) << 4));
                st0 = __builtin_amdgcn_mfma_f32_32x32x16_bf16(a0, bq[ds], st0, 0, 0, 0);
                st1 = __builtin_amdgcn_mfma_f32_32x32x16_bf16(a1, bq[ds], st1, 0, 0, 0);
            }
        }
        __builtin_amdgcn_s_setprio(0);

        // ---- tile max (tree + shfl cross-half exchange) ----
        float tm[8];
#pragma unroll
        for (int i = 0; i < 8; i++)
            tm[i] = fmaxf(fmaxf(st0[i], st0[i + 8]), fmaxf(st1[i], st1[i + 8]));
#pragma unroll
        for (int i = 0; i < 4; i++) tm[i] = fmaxf(tm[i], tm[i + 4]);
        float pm = fmaxf(fmaxf(tm[0], tm[1]), fmaxf(tm[2], tm[3]));
        pm = fmaxf(pm, __shfl_xor(pm, 32));

        // ---- T13 defer-max (exp2 domain): rescale only when max grew past THR=8 ----
        if (!__all(pm <= mrun + 8.f)) {
            const float nm = fmaxf(mrun, pm);
            const float corr = EXP2(mrun - nm);
            mrun = nm;
            lrun *= corr;
#pragma unroll
            for (int i = 0; i < 16; i++) { oacc0[i] *= corr; oacc1[i] *= corr; }
        }

        // ---- p = exp2(st - m); sum (vector tree) ----
        f32x16 p0, p1;
#pragma unroll
        for (int i = 0; i < 16; i++) {
            p0[i] = EXP2(st0[i] - mrun);
            p1[i] = EXP2(st1[i] - mrun);
        }
        float ts[8];
#pragma unroll
        for (int i = 0; i < 8; i++) ts[i] = (p0[i] + p0[i + 8]) + (p1[i] + p1[i + 8]);
#pragma unroll
        for (int i = 0; i < 4; i++) ts[i] += ts[i + 4];
        float ps = (ts[0] + ts[1]) + (ts[2] + ts[3]);
        ps += __shfl_xor(ps, 32);
        lrun += ps;

        // ---- P^T -> bf16 B-operand fragments (cvt_pk + permlane32_swap, T12) ----
        short8 pb[4];
        {
            unsigned int w[8];
#pragma unroll
            for (int p = 0; p < 8; p++) w[p] = cvtpk_bf16(p0[2 * p], p0[2 * p + 1]);
            PLSWAP(w[0], w[2]); PLSWAP(w[1], w[3]);
            PLSWAP(w[4], w[6]); PLSWAP(w[5], w[7]);
            uint4v lo = {w[0], w[1], w[2], w[3]};
            uint4v hi = {w[4], w[5], w[6], w[7]};
            pb[0] = __builtin_bit_cast(short8, lo);
            pb[1] = __builtin_bit_cast(short8, hi);
        }
        {
            unsigned int w[8];
#pragma unroll
            for (int p = 0; p < 8; p++) w[p] = cvtpk_bf16(p1[2 * p], p1[2 * p + 1]);
            PLSWAP(w[0], w[2]); PLSWAP(w[1], w[3]);
            PLSWAP(w[4], w[6]); PLSWAP(w[5], w[7]);
            uint4v lo = {w[0], w[1], w[2], w[3]};
            uint4v hi = {w[4], w[5], w[6], w[7]};
            pb[2] = __builtin_bit_cast(short8, lo);
            pb[3] = __builtin_bit_cast(short8, hi);
        }

        // ---- O^T[d, q] += sum_k V^T[d,k] * P^T[k,q] ----
        __builtin_amdgcn_s_setprio(1);
        {
            const char* vr0 = Vt + (qcol)*128;
            const char* vr1 = Vt + (32 + qcol) * 128;
#pragma unroll
            for (int kb = 0; kb < 4; kb++) {
                const int slot = kb * 2 + g;
                short8 a0 = *(const short8*)(vr0 + ((slot ^ rx7) << 4));
                short8 a1 = *(const short8*)(vr1 + ((slot ^ rx7) << 4));
                oacc0 = __builtin_amdgcn_mfma_f32_32x32x16_bf16(a0, pb[kb], oacc0, 0, 0, 0);
                oacc1 = __builtin_amdgcn_mfma_f32_32x32x16_bf16(a1, pb[kb], oacc1, 0, 0, 0);
            }
        }
        __builtin_amdgcn_s_setprio(0);
    }
#undef ATTN_STAGE

    // ---- epilogue: O[q][d] = O^T[d][q] / lrun ----
    const float inv = 1.f / lrun;
    unsigned short* orow = O + ((size_t)(b * 2048 + q0 + qcol)) * 1024 + h * 64;
#pragma unroll
    for (int dsub = 0; dsub < 2; dsub++)
#pragma unroll
        for (int q4 = 0; q4 < 4; q4++) {
            ushort4v pk;
#pragma unroll
            for (int rr = 0; rr < 4; rr++) {
                float v = (dsub == 0 ? oacc0[q4 * 4 + rr] : oacc1[q4 * 4 + rr]) * inv;
                pk[rr] = f2bf(v);
            }
            const int d0 = dsub * 32 + q4 * 8 + g * 4;
            *(ushort4v*)(orow + d0) = pk;
        }
}

// ---------------- launch ----------------
extern "C" void kernel_launch(void* const* d_in, const int* in_sizes, int n_in,
                              void* d_out, int out_size, void* d_ws, size_t ws_size,
                              hipStream_t stream) {
    const float* query = (const float*)d_in[0];
    const float* key_  = (const float*)d_in[1];
    const float* value = (const float*)d_in[2];
    const float* Wq = (const float*)d_in[3];
    const float* bq = (const float*)d_in[4];
    const float* Wk = (const float*)d_in[5];
    const float* bk = (const float*)d_in[6];
    const float* Wv = (const float*)d_in[7];
    const float* bv = (const float*)d_in[8];
    const float* Wo = (const float*)d_in[9];
    const float* bo = (const float*)d_in[10];

    char* ws = (char*)d_ws;
    unsigned short* Xbf = (unsigned short*)(ws);                    // 16 MB (attn out)
    unsigned short* Wqb = (unsigned short*)(ws + (16ull << 20));    // 2 MB
    unsigned short* Wkb = (unsigned short*)(ws + (18ull << 20));
    unsigned short* Wvb = (unsigned short*)(ws + (20ull << 20));
    unsigned short* Wob = (unsigned short*)(ws + (22ull << 20));
    unsigned short* Qb  = (unsigned short*)(ws + (24ull << 20));    // 16 MB
    unsigned short* Kb  = (unsigned short*)(ws + (40ull << 20));    // 16 MB
    unsigned short* VTb = (unsigned short*)(ws + (56ull << 20));    // 16 MB  (total 72 MB)

    cvtW<<<4096, 256, 0, stream>>>(Wq, Wk, Wv, Wo, Wqb, Wkb, Wvb, Wob);

    // merged Q/K/V projections (fp32 A converted in-kernel, Q pre-scaled for exp2 softmax)
    proj3<<<1536, 256, 0, stream>>>(query, key_, value, Wqb, Wkb, Wvb,
                                    bq, bk, bv, Qb, Kb, VTb);

    attn2<<<1024, 256, 0, stream>>>(Qb, Kb, VTb, Xbf);

    gemm_out<<<512, 256, 0, stream>>>(Xbf, Wob, bo, (float*)d_out);
}